// Round 7
// baseline (454.797 us; speedup 1.0000x reference)
//
#include <hip/hip_runtime.h>
#include <cstdint>
#include <cstddef>

#define N_NODES 100000
#define N_EDGES 1600000
#define F_IN    128
#define H1D     200
#define H2D     50
#define NCLS    10

// K-pitches (multiple of 32 for guard-free MFMA K-loop)
#define P1 256   // layer-1 K: [agg-x(128) | x(128)]
#define P2 416   // layer-2 K: [agg-h1(200) | h1(200) | pad(16)]
#define P3 128   // layer-3 K: [agg(50) | pad(6) | h2@56 (50) | pad(22)]
#define H2OFF 56
// tables:
//   X16_1: x u16 codes, pitch 128 shorts (256 B)
//   Xb   : x bf16, pitch 128 shorts
//   Hcb  : h1 bf16, pitch 200 shorts
//   X10_2: h1 10-bit codes, pitch 64 dwords (256 B)
//   Htab : h2 u16 codes, pitch 64 shorts (128 B)
#define X2PD 64
// LDS A-tile pitches (double as epilogue transpose pitch; bank-spread)
#define HP1 204   // l1: As pitch AND Hs pitch (26.1 KB)
#define AP2 216   // l2: As pitch (27.6 KB)
#define HP2 68    // l2: Hs pitch (aliases As)

// CSR-fill bucketing
#define BSH 9
#define BMASK 511
#define NB 196
#define EPB 8192
#define CAP 9216

typedef __attribute__((ext_vector_type(8))) short short8;
typedef __attribute__((ext_vector_type(4))) float f32x4;

__device__ __forceinline__ unsigned short f2b(float f) {
    union { float f; uint32_t u; } v; v.f = f;
    uint32_t u = v.u;
    return (unsigned short)((u + 0x7fffu + ((u >> 16) & 1u)) >> 16);  // RNE
}

__device__ __forceinline__ uint32_t pkmax_u16(uint32_t a, uint32_t b) {
    uint32_t d;
    asm("v_pk_max_u16 %0, %1, %2" : "=v"(d) : "v"(a), "v"(b));
    return d;
}
__device__ __forceinline__ uint32_t permb(uint32_t hi, uint32_t lo, uint32_t sel) {
    uint32_t d;
    asm("v_perm_b32 %0, %1, %2, %3" : "=v"(d) : "v"(hi), "v"(lo), "v"(sel));
    return d;
}

// order-preserving bf16 <-> u16 code (exact)
__device__ __forceinline__ unsigned short enc16(unsigned short h) {
    return (h & 0x8000u) ? (unsigned short)(~h) : (unsigned short)(h | 0x8000u);
}
__device__ __forceinline__ unsigned short dec16(unsigned short e) {
    return (e & 0x8000u) ? (unsigned short)(e ^ 0x8000u) : (unsigned short)(~e);
}
__device__ __forceinline__ uint32_t dec2(uint32_t p) {
    return (uint32_t)dec16((unsigned short)p) |
           ((uint32_t)dec16((unsigned short)(p >> 16)) << 16);
}

// ---- 10-bit sortable windowed (h1): s + e4 + m5, window [2^-6,2^9) ----
__device__ __forceinline__ uint32_t b2s10(unsigned short h) {
    int m12 = (int)(h & 0x7FFF) - 15488;
    m12 = m12 < 0 ? 0 : (m12 > 2047 ? 2047 : m12);
    uint32_t m10 = (uint32_t)((m12 + 1 + ((m12 >> 2) & 1)) >> 2);
    m10 = m10 > 511u ? 511u : m10;
    return (h & 0x8000) ? (511u - m10) : (512u + m10);
}
__device__ __forceinline__ unsigned short s102b(uint32_t t) {
    if (t >= 512u) { uint32_t mag = t - 512u; return mag ? (unsigned short)((mag << 2) + 15488u) : (unsigned short)0; }
    uint32_t mag = 511u - t;   return mag ? (unsigned short)(0x8000u | ((mag << 2) + 15488u)) : (unsigned short)0;
}
__device__ __forceinline__ void pack10x16(const uint32_t* t, uint32_t* d) {
    d[0] = t[0] | (t[1] << 10) | (t[2] << 20) | (t[3] << 30);
    d[1] = (t[3] >> 2) | (t[4] << 8) | (t[5] << 18) | (t[6] << 28);
    d[2] = (t[6] >> 4) | (t[7] << 6) | (t[8] << 16) | (t[9] << 26);
    d[3] = (t[9] >> 6) | (t[10] << 4) | (t[11] << 14) | (t[12] << 24);
    d[4] = (t[12] >> 8) | (t[13] << 2) | (t[14] << 12) | (t[15] << 22);
}

__device__ __forceinline__ int block_excl_scan_256(int v, int* wsum) {
    const int tid = threadIdx.x;
    const int lane = tid & 63;
    const int wid = tid >> 6;
    int incl = v;
    #pragma unroll
    for (int off = 1; off < 64; off <<= 1) {
        int t = __shfl_up(incl, off, 64);
        if (lane >= off) incl += t;
    }
    if (lane == 63) wsum[wid] = incl;
    __syncthreads();
    if (tid == 0) {
        int s = 0;
        #pragma unroll
        for (int k = 0; k < 4; k++) { int t = wsum[k]; wsum[k] = s; s += t; }
    }
    __syncthreads();
    return wsum[wid] + incl - v;
}

// ---------------------------------------------------------------------------
// CSR build (unchanged)
// ---------------------------------------------------------------------------
__global__ void csr_init(int* __restrict__ g_bcur) {
    int t = threadIdx.x;
    if (t < NB) g_bcur[t] = t * CAP;
}

__global__ __launch_bounds__(256) void csr_p1(const int* __restrict__ src,
                                              const int* __restrict__ dst,
                                              int* __restrict__ g_bcur,
                                              uint32_t* __restrict__ staging, int E) {
    __shared__ int cnt[256];
    __shared__ int base_s[256];
    const int tid = threadIdx.x;
    const int base = blockIdx.x * EPB;
    cnt[tid] = 0;
    __syncthreads();
    #pragma unroll 4
    for (int i = 0; i < EPB / 256; i++) {
        int e = base + i * 256 + tid;
        if (e < E) atomicAdd(&cnt[dst[e] >> BSH], 1);
    }
    __syncthreads();
    int v = cnt[tid];
    if (v > 0) base_s[tid] = atomicAdd(&g_bcur[tid], v);
    cnt[tid] = 0;
    __syncthreads();
    #pragma unroll 4
    for (int i = 0; i < EPB / 256; i++) {
        int e = base + i * 256 + tid;
        if (e < E) {
            int d = dst[e], s = src[e];
            int b = d >> BSH;
            int r = atomicAdd(&cnt[b], 1);
            staging[base_s[b] + r] = ((uint32_t)s << BSH) | (uint32_t)(d & BMASK);
        }
    }
}

__global__ __launch_bounds__(256) void csr_bscan(const int* __restrict__ g_bcur,
                                                 int* __restrict__ g_bbase) {
    __shared__ int wsum[4];
    const int tid = threadIdx.x;
    int v = (tid < NB) ? (g_bcur[tid] - tid * CAP) : 0;
    int excl = block_excl_scan_256(v, wsum);
    if (tid <= NB) g_bbase[tid] = excl;
}

__global__ __launch_bounds__(256) void csr_p2(const uint32_t* __restrict__ staging,
                                              const int* __restrict__ g_bcur,
                                              const int* __restrict__ g_bbase,
                                              int* __restrict__ row_ptr,
                                              int* __restrict__ col_src, int N, int E) {
    __shared__ int cnt[512];
    __shared__ int wsum[4];
    const int tid = threadIdx.x;
    const int nodeBase = blockIdx.x << BSH;
    cnt[tid] = 0; cnt[tid + 256] = 0;
    __syncthreads();
    const int lo_s = blockIdx.x * CAP;
    const int hi_s = g_bcur[blockIdx.x];
    const int colBase = g_bbase[blockIdx.x];
    for (int j = lo_s + tid; j < hi_s; j += 256)
        atomicAdd(&cnt[staging[j] & BMASK], 1);
    __syncthreads();
    int v0 = cnt[2 * tid], v1 = cnt[2 * tid + 1];
    int pexcl = block_excl_scan_256(v0 + v1, wsum);
    __syncthreads();
    cnt[2 * tid]     = colBase + pexcl;
    cnt[2 * tid + 1] = colBase + pexcl + v0;
    int node0 = nodeBase + 2 * tid;
    if (node0 < N)     row_ptr[node0]     = colBase + pexcl;
    if (node0 + 1 < N) row_ptr[node0 + 1] = colBase + pexcl + v0;
    __syncthreads();
    for (int j = lo_s + tid; j < hi_s; j += 256) {
        uint32_t rec = staging[j];
        int p = atomicAdd(&cnt[rec & BMASK], 1);
        col_src[p] = (int)(rec >> BSH);
    }
    if (blockIdx.x == 0 && tid == 0) row_ptr[N] = E;
}

// ---------------------------------------------------------------------------
// prep: transposed bf16 weight tables (unchanged)
// ---------------------------------------------------------------------------
__global__ void build_bt_all(const float* __restrict__ Wl1, const float* __restrict__ Wr1,
                             const float* __restrict__ Wl2, const float* __restrict__ Wr2,
                             const float* __restrict__ Wl3, const float* __restrict__ Wr3,
                             unsigned short* __restrict__ Bt1,
                             unsigned short* __restrict__ Bt2,
                             unsigned short* __restrict__ Bt3) {
    constexpr int S1 = H1D * P1, S2 = H2D * P2, S3 = NCLS * P3;
    int idx = blockIdx.x * blockDim.x + threadIdx.x;
    if (idx < S1) {
        int m = idx / P1, k = idx - m * P1;
        float v = 0.0f;
        if (k < F_IN)            v = Wl1[(size_t)k * H1D + m];
        else if (k < 2 * F_IN)   v = Wr1[(size_t)(k - F_IN) * H1D + m];
        Bt1[idx] = f2b(v);
    } else if (idx < S1 + S2) {
        int j = idx - S1;
        int m = j / P2, k = j - m * P2;
        float v = 0.0f;
        if (k < H1D)             v = Wl2[(size_t)k * H2D + m];
        else if (k < 2 * H1D)    v = Wr2[(size_t)(k - H1D) * H2D + m];
        Bt2[j] = f2b(v);
    } else if (idx < S1 + S2 + S3) {
        int j = idx - S1 - S2;
        int m = j / P3, k = j - m * P3;
        float v = 0.0f;
        if (k < H2D)                          v = Wl3[(size_t)k * NCLS + m];
        else if (k >= H2OFF && k < H2OFF+H2D) v = Wr3[(size_t)(k - H2OFF) * NCLS + m];
        Bt3[j] = f2b(v);
    }
}

// x (f32) -> bf16 Xb (pitch 128) AND u16 codes X16 (pitch 128)
__global__ void conv_x_kernel(const float* __restrict__ x,
                              unsigned short* __restrict__ Xb,
                              unsigned short* __restrict__ X16, int N) {
    int idx = blockIdx.x * blockDim.x + threadIdx.x;
    if (idx >= N * 16) return;
    int row = idx >> 4, g = idx & 15;
    const float* xp = x + (size_t)row * F_IN + g * 8;
    unsigned short h[8];
    #pragma unroll
    for (int i = 0; i < 8; i++) h[i] = f2b(xp[i]);
    ushort4 o0 = {h[0], h[1], h[2], h[3]};
    ushort4 o1 = {h[4], h[5], h[6], h[7]};
    *(ushort4*)(Xb + (size_t)row * 128 + g * 8)     = o0;
    *(ushort4*)(Xb + (size_t)row * 128 + g * 8 + 4) = o1;
    ushort4 c0 = {enc16(h[0]), enc16(h[1]), enc16(h[2]), enc16(h[3])};
    ushort4 c1 = {enc16(h[4]), enc16(h[5]), enc16(h[6]), enc16(h[7])};
    *(ushort4*)(X16 + (size_t)row * 128 + g * 8)     = c0;
    *(ushort4*)(X16 + (size_t)row * 128 + g * 8 + 4) = c1;
}

// ---------------------------------------------------------------------------
// fused layer 1 (v7): gather -> LDS As (pitch HP1); MFMA K-loop with NO
// barriers and NO B in LDS -- b-fragments are per-lane 16-B global loads from
// the L2-resident Bt (102 KB shared by all blocks). A-frag: As (kofs<128) or
// Xb-direct (kofs>=128). Waves fully independent between the 2 barriers;
// epilogue transpose Hs ALIASES As (same pitch HP1). 3 barriers/block.
// ---------------------------------------------------------------------------
__global__ __launch_bounds__(512, 6) void fused_l1(
    const unsigned short* __restrict__ X16,
    const unsigned short* __restrict__ Xb,
    const int* __restrict__ row_ptr, const int* __restrict__ col_src,
    const unsigned short* __restrict__ Bt,
    const float* __restrict__ bias,
    unsigned short* __restrict__ Hcb,
    uint32_t* __restrict__ X10out,
    int N) {
    constexpr int NCT = 13, M = H1D, P = P1;
    __shared__ short As[64 * HP1];        // 26.1 KB; epilogue Hs aliases it
    short* Hs = As;
    const int tid = threadIdx.x;
    const int wv = tid >> 6;
    const int lane = tid & 63;
    const int q = lane >> 4;
    const int mi = lane & 15;
    const int sp = wv >> 2;
    const int tq = wv & 3;
    const int rowBase = blockIdx.x * 64;

    // ---- gather: wave wv aggregates nodes [wv*8, wv*8+8) ----
    {
        const int l = lane & 15;
        const int grp = lane >> 4;          // 4 groups, EPW=4
        const int f0 = l * 8;
        const unsigned short* Xl = X16 + f0;
        for (int n = 0; n < 8; n++) {
            int node = rowBase + wv * 8 + n;
            int beg = 0, end = 0;
            if (node < N) { beg = row_ptr[node]; end = row_ptr[node + 1]; }
            uint32_t t0 = 0, t1 = 0, t2 = 0, t3 = 0;
            auto mrg = [&](uint4 v) {
                t0 = pkmax_u16(t0, v.x); t1 = pkmax_u16(t1, v.y);
                t2 = pkmax_u16(t2, v.z); t3 = pkmax_u16(t3, v.w);
            };
            int j = beg + grp;
            for (; j + 4 < end; j += 8) {
                uint4 a = *(const uint4*)(Xl + (size_t)col_src[j] * 128);
                uint4 b = *(const uint4*)(Xl + (size_t)col_src[j + 4] * 128);
                mrg(a); mrg(b);
            }
            for (; j < end; j += 4)
                mrg(*(const uint4*)(Xl + (size_t)col_src[j] * 128));
            #pragma unroll
            for (int off = 16; off < 64; off <<= 1) {
                t0 = pkmax_u16(t0, (uint32_t)__shfl_xor((int)t0, off, 64));
                t1 = pkmax_u16(t1, (uint32_t)__shfl_xor((int)t1, off, 64));
                t2 = pkmax_u16(t2, (uint32_t)__shfl_xor((int)t2, off, 64));
                t3 = pkmax_u16(t3, (uint32_t)__shfl_xor((int)t3, off, 64));
            }
            if (grp == 0) {
                uint4 o = {0u, 0u, 0u, 0u};
                if (beg != end) {
                    o.x = dec2(t0); o.y = dec2(t1); o.z = dec2(t2); o.w = dec2(t3);
                }
                *(uint4*)(&As[(wv * 8 + n) * HP1 + f0]) = o;
            }
        }
    }
    __syncthreads();   // barrier 1: As agg-half complete

    // ---- MFMA K-loop: NO barriers, b-frags direct from L2-hot Bt ----
    constexpr int TPW = 4;
    f32x4 acc[2][TPW];
    #pragma unroll
    for (int s = 0; s < 2; s++)
        #pragma unroll
        for (int j = 0; j < TPW; j++) acc[s][j] = (f32x4){0.f, 0.f, 0.f, 0.f};
    const int r0g = rowBase + (2 * sp) * 16 + mi;   // tail rows >=N read slack;
    const int r1g = r0g + 16;                       // outputs discarded
    #pragma unroll
    for (int kt = 0; kt < P; kt += 32) {
        const int kofs = kt + q * 8;
        short8 a0, a1;
        if (kofs < 128) {
            a0 = *(const short8*)(&As[((2 * sp) * 16 + mi) * HP1 + kofs]);
            a1 = *(const short8*)(&As[((2 * sp + 1) * 16 + mi) * HP1 + kofs]);
        } else {
            a0 = *(const short8*)(Xb + (size_t)r0g * 128 + (kofs - 128));
            a1 = *(const short8*)(Xb + (size_t)r1g * 128 + (kofs - 128));
        }
        #pragma unroll
        for (int j = 0; j < TPW; j++) {
            int t = tq + 4 * j;
            if (t < NCT) {
                // rows >= M read adjacent ws allocations (garbage) -- only
                // feeds discarded output cols >= M (independent dot products)
                short8 b = *(const short8*)(Bt + (size_t)(t * 16 + mi) * P + kofs);
                acc[0][j] = __builtin_amdgcn_mfma_f32_16x16x32_bf16(a0, b, acc[0][j], 0, 0, 0);
                acc[1][j] = __builtin_amdgcn_mfma_f32_16x16x32_bf16(a1, b, acc[1][j], 0, 0, 0);
            }
        }
    }
    __syncthreads();   // barrier 2: all As a-frag reads done -> Hs writable

    // ---- epilogue: acc -> Hs (alias of As, pitch HP1) ----
    #pragma unroll
    for (int j = 0; j < TPW; j++) {
        int t = tq + 4 * j;
        if (t >= NCT) continue;
        int col = t * 16 + mi;
        if (col >= M) continue;
        float bv = bias[col];
        #pragma unroll
        for (int s = 0; s < 2; s++) {
            int st = 2 * sp + s;
            #pragma unroll
            for (int r = 0; r < 4; r++) {
                int rl = st * 16 + q * 4 + r;
                Hs[rl * HP1 + col] = (short)f2b(acc[s][j][r] + bv);
            }
        }
    }
    __syncthreads();   // barrier 3: Hs complete

    for (int k2 = tid; k2 < 64 * 25; k2 += 512) {
        int r = k2 / 25, c8 = (k2 - r * 25) * 8;
        int row = rowBase + r;
        if (row < N) {
            uint2 lo = *(const uint2*)(&Hs[r * HP1 + c8]);
            uint2 hi = *(const uint2*)(&Hs[r * HP1 + c8 + 4]);
            uint4 v = {lo.x, lo.y, hi.x, hi.y};
            *(uint4*)(Hcb + (size_t)row * 200 + c8) = v;
        }
    }
    for (int k2 = tid; k2 < 64 * 13; k2 += 512) {
        int r = k2 / 13, g = k2 - r * 13;
        int row = rowBase + r;
        if (row >= N) continue;
        uint32_t* op = X10out + (size_t)row * X2PD;
        const short* hp = &Hs[r * HP1 + g * 16];
        if (g < 12) {
            uint2 w0 = *(const uint2*)(hp);
            uint2 w1 = *(const uint2*)(hp + 4);
            uint2 w2 = *(const uint2*)(hp + 8);
            uint2 w3 = *(const uint2*)(hp + 12);
            uint32_t t[16];
            t[0]  = b2s10((unsigned short)(w0.x)); t[1]  = b2s10((unsigned short)(w0.x >> 16));
            t[2]  = b2s10((unsigned short)(w0.y)); t[3]  = b2s10((unsigned short)(w0.y >> 16));
            t[4]  = b2s10((unsigned short)(w1.x)); t[5]  = b2s10((unsigned short)(w1.x >> 16));
            t[6]  = b2s10((unsigned short)(w1.y)); t[7]  = b2s10((unsigned short)(w1.y >> 16));
            t[8]  = b2s10((unsigned short)(w2.x)); t[9]  = b2s10((unsigned short)(w2.x >> 16));
            t[10] = b2s10((unsigned short)(w2.y)); t[11] = b2s10((unsigned short)(w2.y >> 16));
            t[12] = b2s10((unsigned short)(w3.x)); t[13] = b2s10((unsigned short)(w3.x >> 16));
            t[14] = b2s10((unsigned short)(w3.y)); t[15] = b2s10((unsigned short)(w3.y >> 16));
            uint32_t d[5];
            pack10x16(t, d);
            #pragma unroll
            for (int i = 0; i < 5; i++) op[g * 5 + i] = d[i];
        } else {
            uint2 w0 = *(const uint2*)(hp);
            uint2 w1 = *(const uint2*)(hp + 4);
            uint32_t t[8];
            t[0] = b2s10((unsigned short)(w0.x)); t[1] = b2s10((unsigned short)(w0.x >> 16));
            t[2] = b2s10((unsigned short)(w0.y)); t[3] = b2s10((unsigned short)(w0.y >> 16));
            t[4] = b2s10((unsigned short)(w1.x)); t[5] = b2s10((unsigned short)(w1.x >> 16));
            t[6] = b2s10((unsigned short)(w1.y)); t[7] = b2s10((unsigned short)(w1.y >> 16));
            uint32_t d0 = t[0] | (t[1] << 10) | (t[2] << 20) | (t[3] << 30);
            uint32_t d1 = (t[3] >> 2) | (t[4] << 8) | (t[5] << 18) | (t[6] << 28);
            uint32_t d2 = (t[6] >> 4) | (t[7] << 6);
            op[60] = d0; op[61] = d1; op[62] = d2;
        }
    }
}

// ---------------------------------------------------------------------------
// fused layer 2 (v7): same no-barrier/no-LDS-B structure. Gather 10-bit h1
// codes (perm+pk_max) -> As (pitch AP2); a-frag As (<200) / Hcb-direct
// ([200,400)) / zero (>=400). Epilogue Hs (pitch HP2) aliases As.
// ---------------------------------------------------------------------------
__global__ __launch_bounds__(512, 8) void fused_l2(
    const uint32_t* __restrict__ X10,
    const unsigned short* __restrict__ Hcb,
    const int* __restrict__ row_ptr, const int* __restrict__ col_src,
    const unsigned short* __restrict__ Bt,
    const float* __restrict__ bias,
    unsigned short* __restrict__ Htab,
    int N) {
    constexpr int M = H2D, P = P2;
    __shared__ short As[64 * AP2];        // 27.6 KB; epilogue Hs aliases it
    short* Hs = As;
    const int tid = threadIdx.x;
    const int wv = tid >> 6;
    const int lane = tid & 63;
    const int q = lane >> 4;
    const int mi = lane & 15;
    const int sp = wv >> 2;
    const int tq = wv & 3;
    const int rowBase = blockIdx.x * 64;

    // ---- gather (10-bit perm+pk_max): wave wv nodes [wv*8, wv*8+8) ----
    {
        const int l = lane & 31;
        const int grp = lane >> 5;
        const int f0 = l * 8;
        int db = (5 * l) >> 1;
        if (db > 61) db = 61;
        const uint32_t qq = (l & 1) ? 0x02020202u : 0u;
        const uint32_t sel02 = 0x03020100u + qq;
        const uint32_t sel13 = 0x04030201u + qq;
        const uint32_t sel57 = 0x05040302u + qq;
        const uint32_t* Xbp = X10 + db;
        for (int n = 0; n < 8; n++) {
            int node = rowBase + wv * 8 + n;
            int beg = 0, end = 0;
            if (node < N) { beg = row_ptr[node]; end = row_ptr[node + 1]; }
            uint32_t t02 = 0, t13 = 0, t46 = 0, t57 = 0;
            auto mrg = [&](uint32_t A_, uint32_t B_, uint32_t C_) {
                uint32_t u02 = permb(B_, A_, sel02) & 0x3FF003FFu;
                uint32_t u13 = permb(B_, A_, sel13) & 0xFFC00FFCu;
                uint32_t u46 = permb(C_, B_, sel13) & 0x3FF003FFu;
                uint32_t u57 = permb(C_, B_, sel57) & 0xFFC00FFCu;
                t02 = pkmax_u16(t02, u02);
                t13 = pkmax_u16(t13, u13);
                t46 = pkmax_u16(t46, u46);
                t57 = pkmax_u16(t57, u57);
            };
            auto ld = [&](int s) -> uint3 {
                return *(const uint3*)(Xbp + ((uint32_t)s << 6));
            };
            int j = beg + grp;
            for (; j + 6 < end; j += 8) {
                int s0 = col_src[j], s1 = col_src[j + 2];
                int s2 = col_src[j + 4], s3 = col_src[j + 6];
                uint3 a = ld(s0), b = ld(s1), c = ld(s2), d = ld(s3);
                mrg(a.x, a.y, a.z); mrg(b.x, b.y, b.z);
                mrg(c.x, c.y, c.z); mrg(d.x, d.y, d.z);
            }
            for (; j + 2 < end; j += 4) {
                int s0 = col_src[j], s1 = col_src[j + 2];
                uint3 a = ld(s0), b = ld(s1);
                mrg(a.x, a.y, a.z); mrg(b.x, b.y, b.z);
            }
            if (j < end) {
                uint3 a = ld(col_src[j]);
                mrg(a.x, a.y, a.z);
            }
            t02 = pkmax_u16(t02, (uint32_t)__shfl_xor((int)t02, 32, 64));
            t13 = pkmax_u16(t13, (uint32_t)__shfl_xor((int)t13, 32, 64));
            t46 = pkmax_u16(t46, (uint32_t)__shfl_xor((int)t46, 32, 64));
            t57 = pkmax_u16(t57, (uint32_t)__shfl_xor((int)t57, 32, 64));
            if (grp == 0 && l < 25) {
                uint4 o = {0u, 0u, 0u, 0u};
                if (beg != end) {
                    unsigned short h[8];
                    h[0] = s102b(t02 & 0xFFFFu);
                    h[2] = s102b(t02 >> 20);
                    h[1] = s102b((t13 & 0xFFFFu) >> 2);
                    h[3] = s102b(t13 >> 22);
                    h[4] = s102b(t46 & 0xFFFFu);
                    h[6] = s102b(t46 >> 20);
                    h[5] = s102b((t57 & 0xFFFFu) >> 2);
                    h[7] = s102b(t57 >> 22);
                    o.x = (uint32_t)h[0] | ((uint32_t)h[1] << 16);
                    o.y = (uint32_t)h[2] | ((uint32_t)h[3] << 16);
                    o.z = (uint32_t)h[4] | ((uint32_t)h[5] << 16);
                    o.w = (uint32_t)h[6] | ((uint32_t)h[7] << 16);
                }
                *(uint4*)(&As[(wv * 8 + n) * AP2 + f0]) = o;
            }
        }
    }
    __syncthreads();   // barrier 1

    // ---- MFMA K-loop: NO barriers, b-frags direct from L2-hot Bt ----
    f32x4 acc0 = (f32x4){0.f, 0.f, 0.f, 0.f};
    f32x4 acc1 = (f32x4){0.f, 0.f, 0.f, 0.f};
    const int r0g = rowBase + (2 * sp) * 16 + mi;
    const int r1g = r0g + 16;
    #pragma unroll
    for (int kt = 0; kt < P; kt += 32) {
        const int kofs = kt + q * 8;
        short8 a0, a1;
        if (kofs < 200) {
            a0 = *(const short8*)(&As[((2 * sp) * 16 + mi) * AP2 + kofs]);
            a1 = *(const short8*)(&As[((2 * sp + 1) * 16 + mi) * AP2 + kofs]);
        } else if (kofs < 400) {
            a0 = *(const short8*)(Hcb + (size_t)r0g * 200 + (kofs - 200));
            a1 = *(const short8*)(Hcb + (size_t)r1g * 200 + (kofs - 200));
        } else {
            a0 = (short8){0,0,0,0,0,0,0,0};
            a1 = (short8){0,0,0,0,0,0,0,0};
        }
        // rows >= M read past Bt2 (allocated slack) -- discarded cols only
        short8 b = *(const short8*)(Bt + (size_t)(tq * 16 + mi) * P + kofs);
        acc0 = __builtin_amdgcn_mfma_f32_16x16x32_bf16(a0, b, acc0, 0, 0, 0);
        acc1 = __builtin_amdgcn_mfma_f32_16x16x32_bf16(a1, b, acc1, 0, 0, 0);
    }
    __syncthreads();   // barrier 2: As reads done -> Hs writable

    // ---- epilogue: acc -> Hs (enc16, pitch HP2) -> Htab vector writes ----
    {
        int col = tq * 16 + mi;
        if (col < M) {
            float bv = bias[col];
            #pragma unroll
            for (int r = 0; r < 4; r++) {
                int rl0 = (2 * sp) * 16 + q * 4 + r;
                int rl1 = rl0 + 16;
                Hs[rl0 * HP2 + col] = (short)enc16(f2b(acc0[r] + bv));
                Hs[rl1 * HP2 + col] = (short)enc16(f2b(acc1[r] + bv));
            }
        }
    }
    for (int k2 = tid; k2 < 64 * 14; k2 += 512) {
        int r = k2 / 14, c = k2 - r * 14;
        Hs[r * HP2 + H2D + c] = 0;      // code 0 = ultra-negative, pk_max-safe
    }
    __syncthreads();   // barrier 3
    for (int k2 = tid; k2 < 64 * 8; k2 += 512) {
        int r = k2 >> 3, c8 = (k2 & 7) * 8;
        int row = rowBase + r;
        if (row < N) {
            uint2 lo = *(const uint2*)(&Hs[r * HP2 + c8]);
            uint2 hi = *(const uint2*)(&Hs[r * HP2 + c8 + 4]);
            uint4 v = {lo.x, lo.y, hi.x, hi.y};
            *(uint4*)(Htab + (size_t)row * 64 + c8) = v;
        }
    }
}

// ---------------------------------------------------------------------------
// Layer 3 fully fused (unchanged)
// ---------------------------------------------------------------------------
__global__ __launch_bounds__(256) void layer3_fused(
    const unsigned short* __restrict__ Htab,
    const int* __restrict__ row_ptr, const int* __restrict__ col_src,
    const unsigned short* __restrict__ Bt,
    const float* __restrict__ bias,
    float* __restrict__ out, int N) {
    __shared__ short As[64 * 136];
    __shared__ short Bs[640];
    const int tid = threadIdx.x;
    const int wv = tid >> 6;
    const int lane = tid & 63;
    const int rowBase = blockIdx.x * 64;

    {
        const int l = lane & 7;
        const int grp = lane >> 3;
        const int f0 = l * 8;
        const unsigned short* Hl = Htab + f0;
        for (int n = 0; n < 16; n++) {
            int node = rowBase + wv * 16 + n;
            int beg = 0, end = 0;
            if (node < N) { beg = row_ptr[node]; end = row_ptr[node + 1]; }
            uint32_t t0 = 0, t1 = 0, t2 = 0, t3 = 0;
            auto mrg = [&](uint4 v) {
                t0 = pkmax_u16(t0, v.x); t1 = pkmax_u16(t1, v.y);
                t2 = pkmax_u16(t2, v.z); t3 = pkmax_u16(t3, v.w);
            };
            int j = beg + grp;
            for (; j + 8 < end; j += 16) {
                uint4 v0 = *(const uint4*)(Hl + (size_t)col_src[j] * 64);
                uint4 v1 = *(const uint4*)(Hl + (size_t)col_src[j + 8] * 64);
                mrg(v0); mrg(v1);
            }
            if (j < end) mrg(*(const uint4*)(Hl + (size_t)col_src[j] * 64));
            #pragma unroll
            for (int off = 8; off < 64; off <<= 1) {
                t0 = pkmax_u16(t0, (uint32_t)__shfl_xor((int)t0, off, 64));
                t1 = pkmax_u16(t1, (uint32_t)__shfl_xor((int)t1, off, 64));
                t2 = pkmax_u16(t2, (uint32_t)__shfl_xor((int)t2, off, 64));
                t3 = pkmax_u16(t3, (uint32_t)__shfl_xor((int)t3, off, 64));
            }
            if (grp == 0 && f0 < H2D) {
                short* op = &As[(wv * 16 + n) * 136];
                const bool empty = (beg == end);
                if (f0 + 8 <= H2D) {
                    uint4 o = {0u, 0u, 0u, 0u};
                    if (!empty) {
                        o.x = dec2(t0); o.y = dec2(t1);
                        o.z = dec2(t2); o.w = dec2(t3);
                    }
                    *(uint4*)(op + f0) = o;
                } else {
                    uint32_t o2 = empty ? 0u : dec2(t0);
                    *(uint32_t*)(op + f0) = o2;
                }
            }
        }
    }
    for (int k = tid; k < 64 * 25; k += 256) {
        int r = k / 25, c = (k - r * 25) * 2;
        int node = rowBase + r;
        uint32_t v = 0;
        if (node < N) v = dec2(*(const uint32_t*)(Htab + (size_t)node * 64 + c));
        *(uint32_t*)(&As[r * 136 + H2OFF + c]) = v;
    }
    for (int k = tid; k < 64 * 28; k += 256) {
        int r = k / 28, c = k - r * 28;
        int col = (c < 6) ? (50 + c) : (100 + c);
        As[r * 136 + col] = 0;
    }
    __syncthreads();

    const int q = lane >> 4;
    const int mi = lane & 15;
    f32x4 acc = (f32x4){0.f, 0.f, 0.f, 0.f};
    for (int kt = 0; kt < P3; kt += 32) {
        if (tid < 64) {
            int br = tid >> 2;
            int bs = tid & 3;
            uint4 vb = {0u, 0u, 0u, 0u};
            if (br < NCLS) vb = *(const uint4*)(Bt + (size_t)br * P3 + kt + bs * 8);
            *(uint4*)(&Bs[br * 40 + bs * 8]) = vb;
        }
        __syncthreads();
        short8 a = *(const short8*)(&As[(wv * 16 + mi) * 136 + kt + q * 8]);
        short8 b = *(const short8*)(&Bs[mi * 40 + q * 8]);
        acc = __builtin_amdgcn_mfma_f32_16x16x32_bf16(a, b, acc, 0, 0, 0);
        __syncthreads();
    }

    float bv = (mi < NCLS) ? bias[mi] : 0.0f;
    #pragma unroll
    for (int r = 0; r < 4; r++) {
        float v = acc[r] + bv;
        float mx = (mi < NCLS) ? v : -INFINITY;
        #pragma unroll
        for (int off = 1; off < 16; off <<= 1)
            mx = fmaxf(mx, __shfl_xor(mx, off, 64));
        float ex = (mi < NCLS) ? expf(v - mx) : 0.0f;
        float sm = ex;
        #pragma unroll
        for (int off = 1; off < 16; off <<= 1)
            sm += __shfl_xor(sm, off, 64);
        int row = rowBase + wv * 16 + q * 4 + r;
        if (mi < NCLS && row < N)
            out[(size_t)row * NCLS + mi] = v - mx - logf(sm);
    }
}

// ---------------------------------------------------------------------------
extern "C" void kernel_launch(void* const* d_in, const int* in_sizes, int n_in,
                              void* d_out, int out_size, void* d_ws, size_t ws_size,
                              hipStream_t stream) {
    const float* x    = (const float*)d_in[0];
    const int*   eidx = (const int*)d_in[1];
    const float* Wl1  = (const float*)d_in[2];
    const float* b1   = (const float*)d_in[3];
    const float* Wr1  = (const float*)d_in[4];
    const float* Wl2  = (const float*)d_in[5];
    const float* b2   = (const float*)d_in[6];
    const float* Wr2  = (const float*)d_in[7];
    const float* Wl3  = (const float*)d_in[8];
    const float* b3   = (const float*)d_in[9];
    const float* Wr3  = (const float*)d_in[10];
    const int* srcp = eidx;
    const int* dstp = eidx + N_EDGES;
    float* out = (float*)d_out;
    (void)ws_size; (void)in_sizes; (void)n_in; (void)out_size;

    char* w = (char*)d_ws;
    size_t off = 0;
    auto alloc = [&](size_t bytes) -> char* {
        char* p = w + off;
        off += (bytes + 255) & ~(size_t)255;
        return p;
    };
    int* g_bbase  = (int*)alloc(sizeof(int) * 256);
    int* g_bcur   = (int*)alloc(sizeof(int) * 256);
    int* row_ptr  = (int*)alloc(sizeof(int) * (N_NODES + 1));
    int* col_src  = (int*)alloc(sizeof(int) * N_EDGES);
    // Union region Z (32 MB), sequential lifetimes on the serial stream:
    //   staging (7.2 MB, dead after csr_p2)
    //   -> X16_1 (25.6 MB, written by conv_x, dead after fused_l1)
    //   -> Htab  (12.8 MB, written by fused_l2, read by layer3)
    char* Z = alloc(32u * 1024 * 1024);
    uint32_t* staging      = (uint32_t*)Z;
    unsigned short* X16_1  = (unsigned short*)Z;
    unsigned short* Htab   = (unsigned short*)Z;
    unsigned short* Xb    = (unsigned short*)alloc(sizeof(short) * (size_t)N_NODES * 128);
    unsigned short* Hcb   = (unsigned short*)alloc(sizeof(short) * (size_t)N_NODES * 200);
    uint32_t* X10_2       = (uint32_t*)alloc(sizeof(uint32_t) * (size_t)N_NODES * X2PD);
    unsigned short* Bt1 = (unsigned short*)alloc(sizeof(short) * H1D * P1);
    unsigned short* Bt2 = (unsigned short*)alloc(sizeof(short) * H2D * P2);
    unsigned short* Bt3 = (unsigned short*)alloc(sizeof(short) * NCLS * P3);
    // slack: direct-B/direct-A tail overreads (rows >= M / rows >= N) land here
    alloc(64 * 1024);

    // ---- CSR build ----
    const int EDGE_BLKS = (N_EDGES + EPB - 1) / EPB;
    csr_init<<<1, 256, 0, stream>>>(g_bcur);
    csr_p1<<<EDGE_BLKS, 256, 0, stream>>>(srcp, dstp, g_bcur, staging, N_EDGES);
    csr_bscan<<<1, 256, 0, stream>>>(g_bcur, g_bbase);
    csr_p2<<<NB, 256, 0, stream>>>(staging, g_bcur, g_bbase, row_ptr, col_src, N_NODES, N_EDGES);

    // ---- prep ----
    constexpr int BT_TOTAL = H1D * P1 + H2D * P2 + NCLS * P3;
    build_bt_all<<<(BT_TOTAL + 255) / 256, 256, 0, stream>>>(Wl1, Wr1, Wl2, Wr2, Wl3, Wr3, Bt1, Bt2, Bt3);
    conv_x_kernel<<<(N_NODES * 16 + 255) / 256, 256, 0, stream>>>(x, Xb, X16_1, N_NODES);

    const int rowTiles64 = (N_NODES + 63) / 64;

    // ---- layer 1 fused: gather(x codes) + GEMM -> Hcb + X10_2 ----
    fused_l1<<<rowTiles64, 512, 0, stream>>>(X16_1, Xb, row_ptr, col_src, Bt1, b1, Hcb, X10_2, N_NODES);

    // ---- layer 2 fused: gather(h1 codes) + GEMM -> Htab ----
    fused_l2<<<rowTiles64, 512, 0, stream>>>(X10_2, Hcb, row_ptr, col_src, Bt2, b2, Htab, N_NODES);

    // ---- layer 3 fused: gather + GEMM + log_softmax -> out ----
    layer3_fused<<<rowTiles64, 256, 0, stream>>>(Htab, row_ptr, col_src, Bt3, b3, out, N_NODES);
}

// Round 8
// 421.140 us; speedup vs baseline: 1.0799x; 1.0799x over previous
//
#include <hip/hip_runtime.h>
#include <cstdint>
#include <cstddef>

#define N_NODES 100000
#define N_EDGES 1600000
#define F_IN    128
#define H1D     200
#define H2D     50
#define NCLS    10

// packed-pitch per layer (multiple of 32 for guard-free MFMA K-loop)
#define P1 256   // [agg(128) | x(128)]
#define P2 416   // [agg(200) | h1(200) | pad(16)]
#define P3 128   // layer-3 K layout: [agg(50) | pad(6) | h2@56 (50) | pad(22)]
#define H2OFF 56
// gather tables:
//   X16_1: x u16 codes, pitch 128 shorts (256 B = 2 lines)
//   X10_2: h1 10-bit sortable codes, pitch 64 dwords (256 B = 2 lines)
//   Htab : h2 u16 codes, pitch 64 shorts (128 B = 1 line)
#define X2PD 64
// epilogue LDS transpose pitches (bank-spread)
#define HP1 204  // gemm1
#define HP2 68   // gemm2

// CSR-fill bucketing
#define BSH 9
#define BMASK 511
#define NB 196
#define EPB 8192
#define CAP 9216

typedef __attribute__((ext_vector_type(8))) short short8;
typedef __attribute__((ext_vector_type(4))) float f32x4;

__device__ __forceinline__ unsigned short f2b(float f) {
    union { float f; uint32_t u; } v; v.f = f;
    uint32_t u = v.u;
    return (unsigned short)((u + 0x7fffu + ((u >> 16) & 1u)) >> 16);  // RNE
}

// packed unsigned 16-bit max (VOP3P)
__device__ __forceinline__ uint32_t pkmax_u16(uint32_t a, uint32_t b) {
    uint32_t d;
    asm("v_pk_max_u16 %0, %1, %2" : "=v"(d) : "v"(a), "v"(b));
    return d;
}
// byte gather from {hi,lo} dword pair
__device__ __forceinline__ uint32_t permb(uint32_t hi, uint32_t lo, uint32_t sel) {
    uint32_t d;
    asm("v_perm_b32 %0, %1, %2, %3" : "=v"(d) : "v"(hi), "v"(lo), "v"(sel));
    return d;
}

// order-preserving bf16 <-> u16 code (exact; layers 1 & 3)
__device__ __forceinline__ unsigned short enc16(unsigned short h) {
    return (h & 0x8000u) ? (unsigned short)(~h) : (unsigned short)(h | 0x8000u);
}
__device__ __forceinline__ unsigned short dec16(unsigned short e) {
    return (e & 0x8000u) ? (unsigned short)(e ^ 0x8000u) : (unsigned short)(~e);
}
__device__ __forceinline__ uint32_t dec2(uint32_t p) {
    return (uint32_t)dec16((unsigned short)p) |
           ((uint32_t)dec16((unsigned short)(p >> 16)) << 16);
}

// ---- 10-bit sortable windowed (h1 table): s + e4 + m5, window [2^-6,2^9) --
__device__ __forceinline__ uint32_t b2s10(unsigned short h) {
    int m12 = (int)(h & 0x7FFF) - 15488;
    m12 = m12 < 0 ? 0 : (m12 > 2047 ? 2047 : m12);
    uint32_t m10 = (uint32_t)((m12 + 1 + ((m12 >> 2) & 1)) >> 2);   // RNE drop 2 bits
    m10 = m10 > 511u ? 511u : m10;
    return (h & 0x8000) ? (511u - m10) : (512u + m10);
}
__device__ __forceinline__ unsigned short s102b(uint32_t t) {
    if (t >= 512u) { uint32_t mag = t - 512u; return mag ? (unsigned short)((mag << 2) + 15488u) : (unsigned short)0; }
    uint32_t mag = 511u - t;   return mag ? (unsigned short)(0x8000u | ((mag << 2) + 15488u)) : (unsigned short)0;
}
// pack 16 x 10-bit codes -> 5 dwords (LSB-first bit-stream)
__device__ __forceinline__ void pack10x16(const uint32_t* t, uint32_t* d) {
    d[0] = t[0] | (t[1] << 10) | (t[2] << 20) | (t[3] << 30);
    d[1] = (t[3] >> 2) | (t[4] << 8) | (t[5] << 18) | (t[6] << 28);
    d[2] = (t[6] >> 4) | (t[7] << 6) | (t[8] << 16) | (t[9] << 26);
    d[3] = (t[9] >> 6) | (t[10] << 4) | (t[11] << 14) | (t[12] << 24);
    d[4] = (t[12] >> 8) | (t[13] << 2) | (t[14] << 12) | (t[15] << 22);
}

// exclusive scan of one value per thread across a 256-thread block
__device__ __forceinline__ int block_excl_scan_256(int v, int* wsum) {
    const int tid = threadIdx.x;
    const int lane = tid & 63;
    const int wid = tid >> 6;
    int incl = v;
    #pragma unroll
    for (int off = 1; off < 64; off <<= 1) {
        int t = __shfl_up(incl, off, 64);
        if (lane >= off) incl += t;
    }
    if (lane == 63) wsum[wid] = incl;
    __syncthreads();
    if (tid == 0) {
        int s = 0;
        #pragma unroll
        for (int k = 0; k < 4; k++) { int t = wsum[k]; wsum[k] = s; s += t; }
    }
    __syncthreads();
    return wsum[wid] + incl - v;
}

// ---------------------------------------------------------------------------
// CSR build, bucketed, fixed-capacity staging (no histogram pre-pass)
// ---------------------------------------------------------------------------
__global__ void csr_init(int* __restrict__ g_bcur) {
    int t = threadIdx.x;
    if (t < NB) g_bcur[t] = t * CAP;
}

__global__ __launch_bounds__(256) void csr_p1(const int* __restrict__ src,
                                              const int* __restrict__ dst,
                                              int* __restrict__ g_bcur,
                                              uint32_t* __restrict__ staging, int E) {
    __shared__ int cnt[256];
    __shared__ int base_s[256];
    const int tid = threadIdx.x;
    const int base = blockIdx.x * EPB;
    cnt[tid] = 0;
    __syncthreads();
    #pragma unroll 4
    for (int i = 0; i < EPB / 256; i++) {
        int e = base + i * 256 + tid;
        if (e < E) atomicAdd(&cnt[dst[e] >> BSH], 1);
    }
    __syncthreads();
    int v = cnt[tid];
    if (v > 0) base_s[tid] = atomicAdd(&g_bcur[tid], v);
    cnt[tid] = 0;
    __syncthreads();
    #pragma unroll 4
    for (int i = 0; i < EPB / 256; i++) {
        int e = base + i * 256 + tid;
        if (e < E) {
            int d = dst[e], s = src[e];
            int b = d >> BSH;
            int r = atomicAdd(&cnt[b], 1);
            staging[base_s[b] + r] = ((uint32_t)s << BSH) | (uint32_t)(d & BMASK);
        }
    }
}

__global__ __launch_bounds__(256) void csr_bscan(const int* __restrict__ g_bcur,
                                                 int* __restrict__ g_bbase) {
    __shared__ int wsum[4];
    const int tid = threadIdx.x;
    int v = (tid < NB) ? (g_bcur[tid] - tid * CAP) : 0;
    int excl = block_excl_scan_256(v, wsum);
    if (tid <= NB) g_bbase[tid] = excl;   // g_bbase[NB] = E
}

__global__ __launch_bounds__(256) void csr_p2(const uint32_t* __restrict__ staging,
                                              const int* __restrict__ g_bcur,
                                              const int* __restrict__ g_bbase,
                                              int* __restrict__ row_ptr,
                                              int* __restrict__ col_src, int N, int E) {
    __shared__ int cnt[512];
    __shared__ int wsum[4];
    const int tid = threadIdx.x;
    const int nodeBase = blockIdx.x << BSH;
    cnt[tid] = 0; cnt[tid + 256] = 0;
    __syncthreads();
    const int lo_s = blockIdx.x * CAP;
    const int hi_s = g_bcur[blockIdx.x];
    const int colBase = g_bbase[blockIdx.x];
    for (int j = lo_s + tid; j < hi_s; j += 256)
        atomicAdd(&cnt[staging[j] & BMASK], 1);
    __syncthreads();
    int v0 = cnt[2 * tid], v1 = cnt[2 * tid + 1];
    int pexcl = block_excl_scan_256(v0 + v1, wsum);
    __syncthreads();
    cnt[2 * tid]     = colBase + pexcl;
    cnt[2 * tid + 1] = colBase + pexcl + v0;
    int node0 = nodeBase + 2 * tid;
    if (node0 < N)     row_ptr[node0]     = colBase + pexcl;
    if (node0 + 1 < N) row_ptr[node0 + 1] = colBase + pexcl + v0;
    __syncthreads();
    for (int j = lo_s + tid; j < hi_s; j += 256) {
        uint32_t rec = staging[j];
        int p = atomicAdd(&cnt[rec & BMASK], 1);
        col_src[p] = (int)(rec >> BSH);
    }
    if (blockIdx.x == 0 && tid == 0) row_ptr[N] = E;
}

// ---------------------------------------------------------------------------
// prep: all three transposed bf16 weight tables in one kernel
// ---------------------------------------------------------------------------
__global__ void build_bt_all(const float* __restrict__ Wl1, const float* __restrict__ Wr1,
                             const float* __restrict__ Wl2, const float* __restrict__ Wr2,
                             const float* __restrict__ Wl3, const float* __restrict__ Wr3,
                             unsigned short* __restrict__ Bt1,
                             unsigned short* __restrict__ Bt2,
                             unsigned short* __restrict__ Bt3) {
    constexpr int S1 = H1D * P1, S2 = H2D * P2, S3 = NCLS * P3;
    int idx = blockIdx.x * blockDim.x + threadIdx.x;
    if (idx < S1) {
        int m = idx / P1, k = idx - m * P1;
        float v = 0.0f;
        if (k < F_IN)            v = Wl1[(size_t)k * H1D + m];
        else if (k < 2 * F_IN)   v = Wr1[(size_t)(k - F_IN) * H1D + m];
        Bt1[idx] = f2b(v);
    } else if (idx < S1 + S2) {
        int j = idx - S1;
        int m = j / P2, k = j - m * P2;
        float v = 0.0f;
        if (k < H1D)             v = Wl2[(size_t)k * H2D + m];
        else if (k < 2 * H1D)    v = Wr2[(size_t)(k - H1D) * H2D + m];
        Bt2[j] = f2b(v);
    } else if (idx < S1 + S2 + S3) {
        int j = idx - S1 - S2;
        int m = j / P3, k = j - m * P3;
        float v = 0.0f;
        if (k < H2D)                          v = Wl3[(size_t)k * NCLS + m];
        else if (k >= H2OFF && k < H2OFF+H2D) v = Wr3[(size_t)(k - H2OFF) * NCLS + m];
        Bt3[j] = f2b(v);
    }
}

// x (f32) -> bf16 into A1 cols [128,256) AND 16-bit sortable codes into X16_1
__global__ void conv_x_kernel(const float* __restrict__ x,
                              unsigned short* __restrict__ A1,
                              unsigned short* __restrict__ X16, int N) {
    int idx = blockIdx.x * blockDim.x + threadIdx.x;
    if (idx >= N * 16) return;
    int row = idx >> 4, g = idx & 15;          // 8 cols per thread
    const float* xp = x + (size_t)row * F_IN + g * 8;
    unsigned short h[8];
    #pragma unroll
    for (int i = 0; i < 8; i++) h[i] = f2b(xp[i]);
    ushort4 o0 = {h[0], h[1], h[2], h[3]};
    ushort4 o1 = {h[4], h[5], h[6], h[7]};
    *(ushort4*)(A1 + (size_t)row * P1 + F_IN + g * 8) = o0;
    *(ushort4*)(A1 + (size_t)row * P1 + F_IN + g * 8 + 4) = o1;
    ushort4 c0 = {enc16(h[0]), enc16(h[1]), enc16(h[2]), enc16(h[3])};
    ushort4 c1 = {enc16(h[4]), enc16(h[5]), enc16(h[6]), enc16(h[7])};
    *(ushort4*)(X16 + (size_t)row * 128 + g * 8)     = c0;
    *(ushort4*)(X16 + (size_t)row * 128 + g * 8 + 4) = c1;
}

// ---------------------------------------------------------------------------
// segment-max over 16-bit sortable code tables (layer 1). 4-deep gather
// unroll: 16 uint4 lines in flight per wave (was 8) -- MLP for random fill.
// ---------------------------------------------------------------------------
template <int F, int G, int PITCHS>
__global__ __launch_bounds__(256) void agg_max_16(
    const unsigned short* __restrict__ X,
    const int* __restrict__ row_ptr, const int* __restrict__ col_src,
    unsigned short* __restrict__ O, int opitch, int N) {
    static_assert(G == 16 || G == 32, "G must be 16/32");
    constexpr int LOG2G = (G == 16) ? 4 : 5;
    constexpr int EPW = 64 / G;
    const int wave = (blockIdx.x * blockDim.x + threadIdx.x) >> 6;
    const int lane = threadIdx.x & 63;
    if (wave >= N) return;
    const int beg = row_ptr[wave];
    const int end = row_ptr[wave + 1];
    const int l = lane & (G - 1);
    const int grp = lane >> LOG2G;
    const int f0 = l * 8;
    const unsigned short* Xl = X + f0;

    uint32_t t0 = 0, t1 = 0, t2 = 0, t3 = 0;
    auto mrg = [&](uint4 v) {
        t0 = pkmax_u16(t0, v.x); t1 = pkmax_u16(t1, v.y);
        t2 = pkmax_u16(t2, v.z); t3 = pkmax_u16(t3, v.w);
    };
    auto ld = [&](int j) -> uint4 {
        return *(const uint4*)(Xl + (size_t)col_src[j] * PITCHS);
    };

    int j = beg + grp;
    for (; j + 3 * EPW < end; j += 4 * EPW) {      // 4-deep
        uint4 a = ld(j), b = ld(j + EPW), c = ld(j + 2 * EPW), d = ld(j + 3 * EPW);
        mrg(a); mrg(b); mrg(c); mrg(d);
    }
    for (; j + EPW < end; j += 2 * EPW) {
        uint4 a = ld(j), b = ld(j + EPW);
        mrg(a); mrg(b);
    }
    for (; j < end; j += EPW)
        mrg(ld(j));

    #pragma unroll
    for (int off = G; off < 64; off <<= 1) {
        t0 = pkmax_u16(t0, (uint32_t)__shfl_xor((int)t0, off, 64));
        t1 = pkmax_u16(t1, (uint32_t)__shfl_xor((int)t1, off, 64));
        t2 = pkmax_u16(t2, (uint32_t)__shfl_xor((int)t2, off, 64));
        t3 = pkmax_u16(t3, (uint32_t)__shfl_xor((int)t3, off, 64));
    }

    if (grp == 0 && f0 < F) {
        unsigned short* op = O + (size_t)wave * opitch + f0;
        uint4 o = {0u, 0u, 0u, 0u};
        if (beg != end) {
            o.x = dec2(t0); o.y = dec2(t1); o.z = dec2(t2); o.w = dec2(t3);
        }
        *(uint4*)op = o;
    }
}

// ---------------------------------------------------------------------------
// segment-max over the 10-bit packed h1 table (layer 2), perm+pk_max decode.
// 8-deep gather unroll: 16 uint3 gathers in flight per wave (was 8).
// ---------------------------------------------------------------------------
__global__ __launch_bounds__(256) void agg_max_10pk(
    const uint32_t* __restrict__ X10,
    const int* __restrict__ row_ptr, const int* __restrict__ col_src,
    unsigned short* __restrict__ O, int opitch, int N) {
    const int wave = (blockIdx.x * blockDim.x + threadIdx.x) >> 6;
    const int lane = threadIdx.x & 63;
    if (wave >= N) return;
    const int beg = row_ptr[wave];
    const int end = row_ptr[wave + 1];
    const int l = lane & 31;
    const int grp = lane >> 5;
    const int f0 = l * 8;
    int db = (5 * l) >> 1;
    if (db > 61) db = 61;                 // pad lanes clamp in-row (discarded)
    const uint32_t qq = (l & 1) ? 0x02020202u : 0u;
    const uint32_t sel02 = 0x03020100u + qq;
    const uint32_t sel13 = 0x04030201u + qq;
    const uint32_t sel57 = 0x05040302u + qq;
    const uint32_t* Xb = X10 + db;

    uint32_t t02 = 0, t13 = 0, t46 = 0, t57 = 0;
    auto mrg = [&](uint32_t A, uint32_t B, uint32_t C) {
        uint32_t u02 = permb(B, A, sel02) & 0x3FF003FFu;   // f0<<0 | f2<<4
        uint32_t u13 = permb(B, A, sel13) & 0xFFC00FFCu;   // f1<<2 | f3<<6
        uint32_t u46 = permb(C, B, sel13) & 0x3FF003FFu;   // f4<<0 | f6<<4
        uint32_t u57 = permb(C, B, sel57) & 0xFFC00FFCu;   // f5<<2 | f7<<6
        t02 = pkmax_u16(t02, u02);
        t13 = pkmax_u16(t13, u13);
        t46 = pkmax_u16(t46, u46);
        t57 = pkmax_u16(t57, u57);
    };
    auto ld = [&](int s) -> uint3 {
        return *(const uint3*)(Xb + ((uint32_t)s << 6));
    };

    int j = beg + grp;
    for (; j + 14 < end; j += 16) {        // 8 gathers in flight per lane
        int s0 = col_src[j],      s1 = col_src[j + 2];
        int s2 = col_src[j + 4],  s3 = col_src[j + 6];
        int s4 = col_src[j + 8],  s5 = col_src[j + 10];
        int s6 = col_src[j + 12], s7 = col_src[j + 14];
        uint3 a = ld(s0), b = ld(s1), c = ld(s2), d = ld(s3);
        uint3 e = ld(s4), f = ld(s5), g = ld(s6), h = ld(s7);
        mrg(a.x, a.y, a.z); mrg(b.x, b.y, b.z);
        mrg(c.x, c.y, c.z); mrg(d.x, d.y, d.z);
        mrg(e.x, e.y, e.z); mrg(f.x, f.y, f.z);
        mrg(g.x, g.y, g.z); mrg(h.x, h.y, h.z);
    }
    for (; j + 6 < end; j += 8) {
        int s0 = col_src[j], s1 = col_src[j + 2];
        int s2 = col_src[j + 4], s3 = col_src[j + 6];
        uint3 a = ld(s0), b = ld(s1), c = ld(s2), d = ld(s3);
        mrg(a.x, a.y, a.z); mrg(b.x, b.y, b.z);
        mrg(c.x, c.y, c.z); mrg(d.x, d.y, d.z);
    }
    for (; j + 2 < end; j += 4) {
        int s0 = col_src[j], s1 = col_src[j + 2];
        uint3 a = ld(s0), b = ld(s1);
        mrg(a.x, a.y, a.z); mrg(b.x, b.y, b.z);
    }
    if (j < end) {
        uint3 a = ld(col_src[j]);
        mrg(a.x, a.y, a.z);
    }

    t02 = pkmax_u16(t02, (uint32_t)__shfl_xor((int)t02, 32, 64));
    t13 = pkmax_u16(t13, (uint32_t)__shfl_xor((int)t13, 32, 64));
    t46 = pkmax_u16(t46, (uint32_t)__shfl_xor((int)t46, 32, 64));
    t57 = pkmax_u16(t57, (uint32_t)__shfl_xor((int)t57, 32, 64));

    if (grp == 0 && f0 < H1D) {
        unsigned short* op = O + (size_t)wave * opitch + f0;
        uint4 o = {0u, 0u, 0u, 0u};
        if (beg != end) {
            unsigned short h[8];
            h[0] = s102b(t02 & 0xFFFFu);
            h[2] = s102b(t02 >> 20);
            h[1] = s102b((t13 & 0xFFFFu) >> 2);
            h[3] = s102b(t13 >> 22);
            h[4] = s102b(t46 & 0xFFFFu);
            h[6] = s102b(t46 >> 20);
            h[5] = s102b((t57 & 0xFFFFu) >> 2);
            h[7] = s102b(t57 >> 22);
            o.x = (uint32_t)h[0] | ((uint32_t)h[1] << 16);
            o.y = (uint32_t)h[2] | ((uint32_t)h[3] << 16);
            o.z = (uint32_t)h[4] | ((uint32_t)h[5] << 16);
            o.w = (uint32_t)h[6] | ((uint32_t)h[7] << 16);
        }
        *(uint4*)op = o;
    }
}

// ---------------------------------------------------------------------------
// MFMA GEMM v6 (unchanged from r5): 64 rows x all M cols per block, 8 waves,
// LDS double-buffer with ONE barrier per K-step.
// ---------------------------------------------------------------------------
template <int NCT, int MODE>
__global__ __launch_bounds__(512) void gemm_mfma_v6(
    const unsigned short* __restrict__ A, int P,
    const unsigned short* __restrict__ Bt,
    const float* __restrict__ bias,
    unsigned short* __restrict__ Cb, int cbPitch, int cbOff,
    uint32_t* __restrict__ X10out,
    unsigned short* __restrict__ Htab,
    int Nrows, int M) {
    constexpr int CHUNK = 2560 + NCT * 640;        // shorts per buffer (As+Bs)
    constexpr int HSZ = (MODE == 1) ? 64 * HP1 : 64 * HP2;
    constexpr int SSZ = (2 * CHUNK > HSZ) ? 2 * CHUNK : HSZ;
    __shared__ short smem[SSZ];
    short* Hs = smem;   // alias; only touched after the final K-loop barrier
    const int tid = threadIdx.x;
    const int wv = tid >> 6;          // 0..7
    const int lane = tid & 63;
    const int q = lane >> 4;
    const int mi = lane & 15;
    const int sp = wv >> 2;           // strip pair: rows [32sp, 32sp+32)
    const int tq = wv & 3;            // tile group: tiles tq+4j
    const int rowBase = blockIdx.x * 64;

    constexpr int TPW = (NCT + 3) / 4;
    f32x4 acc[2][TPW];
    #pragma unroll
    for (int s = 0; s < 2; s++)
        #pragma unroll
        for (int j = 0; j < TPW; j++) acc[s][j] = (f32x4){0.f, 0.f, 0.f, 0.f};

    // staging: slots [0,256) = A (64 rows x 4 segs), [256,..) = B (NCT*64)
    constexpr int ASLOTS = 256;
    constexpr int BSLOTS = NCT * 64;
    constexpr int TSLOTS = ASLOTS + BSLOTS;
    constexpr int SITERS = (TSLOTS + 511) / 512;
    uint4 rS[SITERS];
    auto issue = [&](int kt) {
        #pragma unroll
        for (int i = 0; i < SITERS; i++) {
            int slot = i * 512 + tid;
            rS[i] = (uint4){0u, 0u, 0u, 0u};
            if (slot < ASLOTS) {
                int gr = rowBase + (slot >> 2);
                if (gr < Nrows)
                    rS[i] = *(const uint4*)(A + (size_t)gr * P + kt + (slot & 3) * 8);
            } else if (slot < TSLOTS) {
                int s = slot - ASLOTS, br = s >> 2;
                if (br < M)
                    rS[i] = *(const uint4*)(Bt + (size_t)br * P + kt + (s & 3) * 8);
            }
        }
    };
    auto commit = [&](int buf) {
        short* base = smem + buf * CHUNK;
        #pragma unroll
        for (int i = 0; i < SITERS; i++) {
            int slot = i * 512 + tid;
            if (slot < ASLOTS) {
                *(uint4*)(&base[(slot >> 2) * 40 + (slot & 3) * 8]) = rS[i];
            } else if (slot < TSLOTS) {
                int s = slot - ASLOTS;
                *(uint4*)(&base[2560 + (s >> 2) * 40 + (s & 3) * 8]) = rS[i];
            }
        }
    };

    int cur = 0;
    issue(0); commit(0);
    __syncthreads();
    for (int kt = 0; kt < P; kt += 32) {
        const bool more = (kt + 32) < P;
        if (more) issue(kt + 32);
        const short* As_ = smem + cur * CHUNK;
        const short* Bs_ = As_ + 2560;
        short8 a0 = *(const short8*)(&As_[((2 * sp    ) * 16 + mi) * 40 + q * 8]);
        short8 a1 = *(const short8*)(&As_[((2 * sp + 1) * 16 + mi) * 40 + q * 8]);
        #pragma unroll
        for (int j = 0; j < TPW; j++) {
            int t = tq + 4 * j;               // wave-uniform
            if (t < NCT) {
                short8 b = *(const short8*)(&Bs_[(t * 16 + mi) * 40 + q * 8]);
                acc[0][j] = __builtin_amdgcn_mfma_f32_16x16x32_bf16(a0, b, acc[0][j], 0, 0, 0);
                acc[1][j] = __builtin_amdgcn_mfma_f32_16x16x32_bf16(a1, b, acc[1][j], 0, 0, 0);
            }
        }
        if (more) commit(cur ^ 1);
        __syncthreads();
        cur ^= 1;
    }

    // ---- epilogue: acc -> Hs (LDS transpose; bank-spread pitch) ----
    // D layout: col = lane&15, row = (lane>>4)*4 + reg  [verified m89/m91]
    constexpr int HP = (MODE == 1) ? HP1 : HP2;
    #pragma unroll
    for (int j = 0; j < TPW; j++) {
        int t = tq + 4 * j;
        if (t >= NCT) continue;
        int col = t * 16 + mi;
        if (col >= M) continue;
        float bv = bias[col];
        #pragma unroll
        for (int s = 0; s < 2; s++) {
            int st = 2 * sp + s;
            #pragma unroll
            for (int r = 0; r < 4; r++) {
                int rl = st * 16 + q * 4 + r;
                float v = acc[s][j][r] + bv;
                unsigned short h = f2b(v);
                if constexpr (MODE == 1) Hs[rl * HP + col] = (short)h;
                else                     Hs[rl * HP + col] = (short)enc16(h);
            }
        }
    }
    if constexpr (MODE == 2) {
        // zero Hs pad cols [50,64) -- code 0 is ultra-negative, pk_max-safe
        for (int k = tid; k < 64 * 14; k += 512) {
            int r = k / 14, c = k - r * 14;
            Hs[r * HP2 + H2D + c] = 0;
        }
    }
    __syncthreads();

    if constexpr (MODE == 1) {
        // vectorized Cb write: cols [200,400) from Hs cols [0,200)
        for (int k = tid; k < 64 * 25; k += 512) {
            int r = k / 25, c8 = (k - r * 25) * 8;
            int row = rowBase + r;
            if (row < Nrows) {
                uint2 lo = *(const uint2*)(&Hs[r * HP1 + c8]);
                uint2 hi = *(const uint2*)(&Hs[r * HP1 + c8 + 4]);
                uint4 v = {lo.x, lo.y, hi.x, hi.y};
                *(uint4*)(Cb + (size_t)row * cbPitch + cbOff + c8) = v;
            }
        }
        // zero A2 pad cols [400,416) (vectorized)
        for (int k = tid; k < 64 * 2; k += 512) {
            int r = k >> 1, c = (k & 1) * 8;
            int row = rowBase + r;
            if (row < Nrows)
                *(uint4*)(Cb + (size_t)row * cbPitch + 2 * H1D + c) = (uint4){0u, 0u, 0u, 0u};
        }
        // pack h1 (bf16 in Hs) -> 10-bit sortable table
        for (int k = tid; k < 64 * 13; k += 512) {
            int r = k / 13, g = k - r * 13;
            int row = rowBase + r;
            if (row >= Nrows) continue;
            uint32_t* op = X10out + (size_t)row * X2PD;
            const short* hp = &Hs[r * HP1 + g * 16];
            if (g < 12) {
                uint2 w0 = *(const uint2*)(hp);
                uint2 w1 = *(const uint2*)(hp + 4);
                uint2 w2 = *(const uint2*)(hp + 8);
                uint2 w3 = *(const uint2*)(hp + 12);
                uint32_t t[16];
                t[0]  = b2s10((unsigned short)(w0.x)); t[1]  = b2s10((unsigned short)(w0.x >> 16));
                t[2]  = b2s10((unsigned short)(w0.y)); t[3]  = b2s10((unsigned short)(w0.y >> 16));
                t[4]  = b2s10((unsigned short)(w1.x)); t[5]  = b2s10((unsigned short)(w1.x >> 16));
                t[6]  = b2s10((unsigned short)(w1.y)); t[7]  = b2s10((unsigned short)(w1.y >> 16));
                t[8]  = b2s10((unsigned short)(w2.x)); t[9]  = b2s10((unsigned short)(w2.x >> 16));
                t[10] = b2s10((unsigned short)(w2.y)); t[11] = b2s10((unsigned short)(w2.y >> 16));
                t[12] = b2s10((unsigned short)(w3.x)); t[13] = b2s10((unsigned short)(w3.x >> 16));
                t[14] = b2s10((unsigned short)(w3.y)); t[15] = b2s10((unsigned short)(w3.y >> 16));
                uint32_t d[5];
                pack10x16(t, d);
                #pragma unroll
                for (int i = 0; i < 5; i++) op[g * 5 + i] = d[i];
            } else {
                uint2 w0 = *(const uint2*)(hp);
                uint2 w1 = *(const uint2*)(hp + 4);
                uint32_t t[8];
                t[0] = b2s10((unsigned short)(w0.x)); t[1] = b2s10((unsigned short)(w0.x >> 16));
                t[2] = b2s10((unsigned short)(w0.y)); t[3] = b2s10((unsigned short)(w0.y >> 16));
                t[4] = b2s10((unsigned short)(w1.x)); t[5] = b2s10((unsigned short)(w1.x >> 16));
                t[6] = b2s10((unsigned short)(w1.y)); t[7] = b2s10((unsigned short)(w1.y >> 16));
                uint32_t d0 = t[0] | (t[1] << 10) | (t[2] << 20) | (t[3] << 30);
                uint32_t d1 = (t[3] >> 2) | (t[4] << 8) | (t[5] << 18) | (t[6] << 28);
                uint32_t d2 = (t[6] >> 4) | (t[7] << 6);
                op[60] = d0; op[61] = d1; op[62] = d2;
            }
        }
    }
    if constexpr (MODE == 2) {
        // vectorized Htab write (cols 0..63 incl. zeroed pads)
        for (int k = tid; k < 64 * 8; k += 512) {
            int r = k >> 3, c8 = (k & 7) * 8;
            int row = rowBase + r;
            if (row < Nrows) {
                uint2 lo = *(const uint2*)(&Hs[r * HP2 + c8]);
                uint2 hi = *(const uint2*)(&Hs[r * HP2 + c8 + 4]);
                uint4 v = {lo.x, lo.y, hi.x, hi.y};
                *(uint4*)(Htab + (size_t)row * 64 + c8) = v;
            }
        }
    }
}

// ---------------------------------------------------------------------------
// Layer 3 fully fused: gather segment-max(h2 codes) + self h2 into an LDS
// A-tile, then K=128 MFMA + bias + log_softmax -> fp32 out. 64 rows/block.
// Gather deepened to 4 outstanding lines per lane-group.
// ---------------------------------------------------------------------------
__global__ __launch_bounds__(256) void layer3_fused(
    const unsigned short* __restrict__ Htab,
    const int* __restrict__ row_ptr, const int* __restrict__ col_src,
    const unsigned short* __restrict__ Bt,
    const float* __restrict__ bias,
    float* __restrict__ out, int N) {
    __shared__ short As[64 * 136];
    __shared__ short Bs[640];
    const int tid = threadIdx.x;
    const int wv = tid >> 6;
    const int lane = tid & 63;
    const int rowBase = blockIdx.x * 64;

    {
        const int l = lane & 7;
        const int grp = lane >> 3;
        const int f0 = l * 8;
        const unsigned short* Hl = Htab + f0;
        for (int n = 0; n < 16; n++) {
            int node = rowBase + wv * 16 + n;
            int beg = 0, end = 0;
            if (node < N) { beg = row_ptr[node]; end = row_ptr[node + 1]; }
            uint32_t t0 = 0, t1 = 0, t2 = 0, t3 = 0;
            auto mrg = [&](uint4 v) {
                t0 = pkmax_u16(t0, v.x); t1 = pkmax_u16(t1, v.y);
                t2 = pkmax_u16(t2, v.z); t3 = pkmax_u16(t3, v.w);
            };
            auto ld = [&](int j) -> uint4 {
                return *(const uint4*)(Hl + (size_t)col_src[j] * 64);
            };
            int j = beg + grp;
            for (; j + 24 < end; j += 32) {            // 4-deep
                uint4 v0 = ld(j), v1 = ld(j + 8), v2 = ld(j + 16), v3 = ld(j + 24);
                mrg(v0); mrg(v1); mrg(v2); mrg(v3);
            }
            for (; j + 8 < end; j += 16) {
                uint4 v0 = ld(j), v1 = ld(j + 8);
                mrg(v0); mrg(v1);
            }
            if (j < end) mrg(ld(j));
            #pragma unroll
            for (int off = 8; off < 64; off <<= 1) {
                t0 = pkmax_u16(t0, (uint32_t)__shfl_xor((int)t0, off, 64));
                t1 = pkmax_u16(t1, (uint32_t)__shfl_xor((int)t1, off, 64));
                t2 = pkmax_u16(t2, (uint32_t)__shfl_xor((int)t2, off, 64));
                t3 = pkmax_u16(t3, (uint32_t)__shfl_xor((int)t3, off, 64));
            }
            if (grp == 0 && f0 < H2D) {
                short* op = &As[(wv * 16 + n) * 136];
                const bool empty = (beg == end);
                if (f0 + 8 <= H2D) {
                    uint4 o = {0u, 0u, 0u, 0u};
                    if (!empty) {
                        o.x = dec2(t0); o.y = dec2(t1);
                        o.z = dec2(t2); o.w = dec2(t3);
                    }
                    *(uint4*)(op + f0) = o;
                } else {  // l==6: cols 48,49 only
                    uint32_t o2 = empty ? 0u : dec2(t0);
                    *(uint32_t*)(op + f0) = o2;
                }
            }
        }
    }
    for (int k = tid; k < 64 * 25; k += 256) {
        int r = k / 25, c = (k - r * 25) * 2;
        int node = rowBase + r;
        uint32_t v = 0;
        if (node < N) v = dec2(*(const uint32_t*)(Htab + (size_t)node * 64 + c));
        *(uint32_t*)(&As[r * 136 + H2OFF + c]) = v;
    }
    for (int k = tid; k < 64 * 28; k += 256) {
        int r = k / 28, c = k - r * 28;
        int col = (c < 6) ? (50 + c) : (100 + c);
        As[r * 136 + col] = 0;
    }
    __syncthreads();

    const int q = lane >> 4;
    const int mi = lane & 15;
    f32x4 acc = (f32x4){0.f, 0.f, 0.f, 0.f};
    for (int kt = 0; kt < P3; kt += 32) {
        if (tid < 64) {
            int br = tid >> 2;
            int bs = tid & 3;
            uint4 vb = {0u, 0u, 0u, 0u};
            if (br < NCLS) vb = *(const uint4*)(Bt + (size_t)br * P3 + kt + bs * 8);
            *(uint4*)(&Bs[br * 40 + bs * 8]) = vb;
        }
        __syncthreads();
        short8 a = *(const short8*)(&As[(wv * 16 + mi) * 136 + kt + q * 8]);
        short8 b = *(const short8*)(&Bs[mi * 40 + q * 8]);
        acc = __builtin_amdgcn_mfma_f32_16x16x32_bf16(a, b, acc, 0, 0, 0);
        __syncthreads();
    }

    float bv = (mi < NCLS) ? bias[mi] : 0.0f;
    #pragma unroll
    for (int r = 0; r < 4; r++) {
        float v = acc[r] + bv;
        float mx = (mi < NCLS) ? v : -INFINITY;
        #pragma unroll
        for (int off = 1; off < 16; off <<= 1)
            mx = fmaxf(mx, __shfl_xor(mx, off, 64));
        float ex = (mi < NCLS) ? expf(v - mx) : 0.0f;
        float sm = ex;
        #pragma unroll
        for (int off = 1; off < 16; off <<= 1)
            sm += __shfl_xor(sm, off, 64);
        int row = rowBase + wv * 16 + q * 4 + r;
        if (mi < NCLS && row < N)
            out[(size_t)row * NCLS + mi] = v - mx - logf(sm);
    }
}

// ---------------------------------------------------------------------------
extern "C" void kernel_launch(void* const* d_in, const int* in_sizes, int n_in,
                              void* d_out, int out_size, void* d_ws, size_t ws_size,
                              hipStream_t stream) {
    const float* x    = (const float*)d_in[0];
    const int*   eidx = (const int*)d_in[1];
    const float* Wl1  = (const float*)d_in[2];
    const float* b1   = (const float*)d_in[3];
    const float* Wr1  = (const float*)d_in[4];
    const float* Wl2  = (const float*)d_in[5];
    const float* b2   = (const float*)d_in[6];
    const float* Wr2  = (const float*)d_in[7];
    const float* Wl3  = (const float*)d_in[8];
    const float* b3   = (const float*)d_in[9];
    const float* Wr3  = (const float*)d_in[10];
    const int* srcp = eidx;
    const int* dstp = eidx + N_EDGES;
    float* out = (float*)d_out;
    (void)ws_size; (void)in_sizes; (void)n_in; (void)out_size;

    char* w = (char*)d_ws;
    size_t off = 0;
    auto alloc = [&](size_t bytes) -> char* {
        char* p = w + off;
        off += (bytes + 255) & ~(size_t)255;
        return p;
    };
    int* g_bbase  = (int*)alloc(sizeof(int) * 256);
    int* g_bcur   = (int*)alloc(sizeof(int) * 256);
    int* row_ptr  = (int*)alloc(sizeof(int) * (N_NODES + 1));
    int* col_src  = (int*)alloc(sizeof(int) * N_EDGES);
    // Union region Z (32 MB), sequential lifetimes on the serial stream:
    //   staging (7.2 MB, dead after csr_p2)
    //   -> X16_1 (25.6 MB, written by conv_x, dead after agg1)
    //   -> X10_2 (25.6 MB, written by gemm1, dead after agg2)
    char* Z = alloc(32u * 1024 * 1024);
    uint32_t* staging      = (uint32_t*)Z;
    unsigned short* X16_1  = (unsigned short*)Z;
    uint32_t* X10_2        = (uint32_t*)Z;
    unsigned short* A1  = (unsigned short*)alloc(sizeof(short) * (size_t)N_NODES * P1);
    unsigned short* A2  = (unsigned short*)alloc(sizeof(short) * (size_t)N_NODES * P2);
    unsigned short* Bt1 = (unsigned short*)alloc(sizeof(short) * H1D * P1);
    unsigned short* Bt2 = (unsigned short*)alloc(sizeof(short) * H2D * P2);
    unsigned short* Bt3 = (unsigned short*)alloc(sizeof(short) * NCLS * P3);
    // h2 code gather table (12.8 MB) overlays A1 (dead after gemm1).
    unsigned short* X16_3 = A1;

    // ---- CSR build (bucketed, fixed-capacity staging) ----
    const int EDGE_BLKS = (N_EDGES + EPB - 1) / EPB;
    csr_init<<<1, 256, 0, stream>>>(g_bcur);
    csr_p1<<<EDGE_BLKS, 256, 0, stream>>>(srcp, dstp, g_bcur, staging, N_EDGES);
    csr_bscan<<<1, 256, 0, stream>>>(g_bcur, g_bbase);
    csr_p2<<<NB, 256, 0, stream>>>(staging, g_bcur, g_bbase, row_ptr, col_src, N_NODES, N_EDGES);

    // ---- prep: weights (1 kernel) + x conversion ----
    constexpr int BT_TOTAL = H1D * P1 + H2D * P2 + NCLS * P3;
    build_bt_all<<<(BT_TOTAL + 255) / 256, 256, 0, stream>>>(Wl1, Wr1, Wl2, Wr2, Wl3, Wr3, Bt1, Bt2, Bt3);
    conv_x_kernel<<<(N_NODES * 16 + 255) / 256, 256, 0, stream>>>(x, A1, X16_1, N_NODES);

    const int aggBlocks = (N_NODES + 3) / 4;
    const int rowTiles64 = (N_NODES + 63) / 64;

    // ---- layer 1: u16-code agg(x) -> gemm1 (h1 -> A2 + fused 10-bit pack) --
    agg_max_16<F_IN, 16, 128><<<aggBlocks, 256, 0, stream>>>(X16_1, row_ptr, col_src, A1, P1, N_NODES);
    gemm_mfma_v6<13, 1><<<rowTiles64, 512, 0, stream>>>(A1, P1, Bt1, b1, A2, P2, H1D, X10_2, nullptr, N_NODES, H1D);

    // ---- layer 2: 10-bit perm/pk agg(h1) -> gemm2 (h2 -> u16 code table) ----
    agg_max_10pk<<<aggBlocks, 256, 0, stream>>>(X10_2, row_ptr, col_src, A2, P2, N_NODES);
    gemm_mfma_v6<4, 2><<<rowTiles64, 512, 0, stream>>>(A2, P2, Bt2, b2, nullptr, 0, 0, nullptr, X16_3, N_NODES, H2D);

    // ---- layer 3: fully fused gather + GEMM + log_softmax -> out ----
    layer3_fused<<<rowTiles64, 256, 0, stream>>>(X16_3, row_ptr, col_src, Bt3, b3, out, N_NODES);
}

// Round 9
// 418.791 us; speedup vs baseline: 1.0860x; 1.0056x over previous
//
#include <hip/hip_runtime.h>
#include <cstdint>
#include <cstddef>

#define N_NODES 100000
#define N_EDGES 1600000
#define F_IN    128
#define H1D     200
#define H2D     50
#define NCLS    10

// packed-pitch per layer (multiple of 32 for guard-free MFMA K-loop)
#define P1 256   // [agg(128) | x(128)]
#define P2 416   // [agg(200) | h1(200) | pad(16)]
#define P3 128   // layer-3 K layout: [agg(50) | pad(6) | h2@56 (50) | pad(22)]
#define H2OFF 56
// gather tables:
//   X16_1: x u16 codes, pitch 128 shorts (256 B = 2 lines)
//   X10_2: h1 10-bit sortable codes, pitch 64 dwords (256 B = 2 lines)
//   Htab : h2 u16 codes, pitch 64 shorts (128 B = 1 line)
#define X2PD 64
// epilogue LDS transpose pitches (bank-spread)
#define HP1 204  // gemm1
#define HP2 68   // gemm2

// CSR-fill bucketing
#define BSH 9
#define BMASK 511
#define NB 196
#define EPB 8192
#define CAP 9216

typedef __attribute__((ext_vector_type(8))) short short8;
typedef __attribute__((ext_vector_type(4))) float f32x4;

__device__ __forceinline__ unsigned short f2b(float f) {
    union { float f; uint32_t u; } v; v.f = f;
    uint32_t u = v.u;
    return (unsigned short)((u + 0x7fffu + ((u >> 16) & 1u)) >> 16);  // RNE
}

// packed unsigned 16-bit max (VOP3P)
__device__ __forceinline__ uint32_t pkmax_u16(uint32_t a, uint32_t b) {
    uint32_t d;
    asm("v_pk_max_u16 %0, %1, %2" : "=v"(d) : "v"(a), "v"(b));
    return d;
}
// byte gather from {hi,lo} dword pair
__device__ __forceinline__ uint32_t permb(uint32_t hi, uint32_t lo, uint32_t sel) {
    uint32_t d;
    asm("v_perm_b32 %0, %1, %2, %3" : "=v"(d) : "v"(hi), "v"(lo), "v"(sel));
    return d;
}

// order-preserving bf16 <-> u16 code (exact; layers 1 & 3)
__device__ __forceinline__ unsigned short enc16(unsigned short h) {
    return (h & 0x8000u) ? (unsigned short)(~h) : (unsigned short)(h | 0x8000u);
}
__device__ __forceinline__ unsigned short dec16(unsigned short e) {
    return (e & 0x8000u) ? (unsigned short)(e ^ 0x8000u) : (unsigned short)(~e);
}
__device__ __forceinline__ uint32_t dec2(uint32_t p) {
    return (uint32_t)dec16((unsigned short)p) |
           ((uint32_t)dec16((unsigned short)(p >> 16)) << 16);
}

// ---- 10-bit sortable windowed (h1 table): s + e4 + m5, window [2^-6,2^9) --
__device__ __forceinline__ uint32_t b2s10(unsigned short h) {
    int m12 = (int)(h & 0x7FFF) - 15488;
    m12 = m12 < 0 ? 0 : (m12 > 2047 ? 2047 : m12);
    uint32_t m10 = (uint32_t)((m12 + 1 + ((m12 >> 2) & 1)) >> 2);   // RNE drop 2 bits
    m10 = m10 > 511u ? 511u : m10;
    return (h & 0x8000) ? (511u - m10) : (512u + m10);
}
__device__ __forceinline__ unsigned short s102b(uint32_t t) {
    if (t >= 512u) { uint32_t mag = t - 512u; return mag ? (unsigned short)((mag << 2) + 15488u) : (unsigned short)0; }
    uint32_t mag = 511u - t;   return mag ? (unsigned short)(0x8000u | ((mag << 2) + 15488u)) : (unsigned short)0;
}
// pack 16 x 10-bit codes -> 5 dwords (LSB-first bit-stream)
__device__ __forceinline__ void pack10x16(const uint32_t* t, uint32_t* d) {
    d[0] = t[0] | (t[1] << 10) | (t[2] << 20) | (t[3] << 30);
    d[1] = (t[3] >> 2) | (t[4] << 8) | (t[5] << 18) | (t[6] << 28);
    d[2] = (t[6] >> 4) | (t[7] << 6) | (t[8] << 16) | (t[9] << 26);
    d[3] = (t[9] >> 6) | (t[10] << 4) | (t[11] << 14) | (t[12] << 24);
    d[4] = (t[12] >> 8) | (t[13] << 2) | (t[14] << 12) | (t[15] << 22);
}

// exclusive scan of one value per thread across a 256-thread block
__device__ __forceinline__ int block_excl_scan_256(int v, int* wsum) {
    const int tid = threadIdx.x;
    const int lane = tid & 63;
    const int wid = tid >> 6;
    int incl = v;
    #pragma unroll
    for (int off = 1; off < 64; off <<= 1) {
        int t = __shfl_up(incl, off, 64);
        if (lane >= off) incl += t;
    }
    if (lane == 63) wsum[wid] = incl;
    __syncthreads();
    if (tid == 0) {
        int s = 0;
        #pragma unroll
        for (int k = 0; k < 4; k++) { int t = wsum[k]; wsum[k] = s; s += t; }
    }
    __syncthreads();
    return wsum[wid] + incl - v;
}

// ---------------------------------------------------------------------------
// prep_all: csr_init (block 0) + weight tables + x conversion, one launch.
// All three parts are mutually independent.
// ---------------------------------------------------------------------------
__global__ __launch_bounds__(256) void prep_all(
    const float* __restrict__ Wl1, const float* __restrict__ Wr1,
    const float* __restrict__ Wl2, const float* __restrict__ Wr2,
    const float* __restrict__ Wl3, const float* __restrict__ Wr3,
    unsigned short* __restrict__ Bt1, unsigned short* __restrict__ Bt2,
    unsigned short* __restrict__ Bt3,
    const float* __restrict__ x,
    unsigned short* __restrict__ A1, unsigned short* __restrict__ X16,
    int* __restrict__ g_bcur, int N) {
    constexpr int S1 = H1D * P1, S2 = H2D * P2, S3 = NCLS * P3;
    constexpr int BT_BLOCKS = (S1 + S2 + S3 + 255) / 256;
    const int bid = blockIdx.x;
    const int tid = threadIdx.x;
    if (bid == 0 && tid < NB) g_bcur[tid] = tid * CAP;
    if (bid < BT_BLOCKS) {
        int idx = bid * 256 + tid;
        if (idx < S1) {
            int m = idx / P1, k = idx - m * P1;
            float v = 0.0f;
            if (k < F_IN)            v = Wl1[(size_t)k * H1D + m];
            else if (k < 2 * F_IN)   v = Wr1[(size_t)(k - F_IN) * H1D + m];
            Bt1[idx] = f2b(v);
        } else if (idx < S1 + S2) {
            int j = idx - S1;
            int m = j / P2, k = j - m * P2;
            float v = 0.0f;
            if (k < H1D)             v = Wl2[(size_t)k * H2D + m];
            else if (k < 2 * H1D)    v = Wr2[(size_t)(k - H1D) * H2D + m];
            Bt2[j] = f2b(v);
        } else if (idx < S1 + S2 + S3) {
            int j = idx - S1 - S2;
            int m = j / P3, k = j - m * P3;
            float v = 0.0f;
            if (k < H2D)                          v = Wl3[(size_t)k * NCLS + m];
            else if (k >= H2OFF && k < H2OFF+H2D) v = Wr3[(size_t)(k - H2OFF) * NCLS + m];
            Bt3[j] = f2b(v);
        }
    } else {
        int idx = (bid - BT_BLOCKS) * 256 + tid;
        if (idx < N * 16) {
            int row = idx >> 4, g = idx & 15;          // 8 cols per thread
            const float* xp = x + (size_t)row * F_IN + g * 8;
            unsigned short h[8];
            #pragma unroll
            for (int i = 0; i < 8; i++) h[i] = f2b(xp[i]);
            ushort4 o0 = {h[0], h[1], h[2], h[3]};
            ushort4 o1 = {h[4], h[5], h[6], h[7]};
            *(ushort4*)(A1 + (size_t)row * P1 + F_IN + g * 8) = o0;
            *(ushort4*)(A1 + (size_t)row * P1 + F_IN + g * 8 + 4) = o1;
            ushort4 c0 = {enc16(h[0]), enc16(h[1]), enc16(h[2]), enc16(h[3])};
            ushort4 c1 = {enc16(h[4]), enc16(h[5]), enc16(h[6]), enc16(h[7])};
            *(ushort4*)(X16 + (size_t)row * 128 + g * 8)     = c0;
            *(ushort4*)(X16 + (size_t)row * 128 + g * 8 + 4) = c1;
        }
    }
}

// ---------------------------------------------------------------------------
// CSR build, bucketed, fixed-capacity staging
// ---------------------------------------------------------------------------
__global__ __launch_bounds__(256) void csr_p1(const int* __restrict__ src,
                                              const int* __restrict__ dst,
                                              int* __restrict__ g_bcur,
                                              uint32_t* __restrict__ staging, int E) {
    __shared__ int cnt[256];
    __shared__ int base_s[256];
    const int tid = threadIdx.x;
    const int base = blockIdx.x * EPB;
    cnt[tid] = 0;
    __syncthreads();
    #pragma unroll 4
    for (int i = 0; i < EPB / 256; i++) {
        int e = base + i * 256 + tid;
        if (e < E) atomicAdd(&cnt[dst[e] >> BSH], 1);
    }
    __syncthreads();
    int v = cnt[tid];
    if (v > 0) base_s[tid] = atomicAdd(&g_bcur[tid], v);
    cnt[tid] = 0;
    __syncthreads();
    #pragma unroll 4
    for (int i = 0; i < EPB / 256; i++) {
        int e = base + i * 256 + tid;
        if (e < E) {
            int d = dst[e], s = src[e];
            int b = d >> BSH;
            int r = atomicAdd(&cnt[b], 1);
            staging[base_s[b] + r] = ((uint32_t)s << BSH) | (uint32_t)(d & BMASK);
        }
    }
}

// csr_p2 with INLINE bucket-base scan (csr_bscan launch eliminated):
// colBase = sum over buckets b < blockIdx.x of (g_bcur[b] - b*CAP).
__global__ __launch_bounds__(256) void csr_p2(const uint32_t* __restrict__ staging,
                                              const int* __restrict__ g_bcur,
                                              int* __restrict__ row_ptr,
                                              int* __restrict__ col_src, int N, int E) {
    __shared__ int cnt[512];
    __shared__ int wsum[4];
    __shared__ int cb_s;
    const int tid = threadIdx.x;
    const int nodeBase = blockIdx.x << BSH;
    cnt[tid] = 0; cnt[tid + 256] = 0;
    int bv = (tid < NB && tid < blockIdx.x) ? (g_bcur[tid] - tid * CAP) : 0;
    #pragma unroll
    for (int off = 32; off; off >>= 1) bv += __shfl_down(bv, off, 64);
    if ((tid & 63) == 0) wsum[tid >> 6] = bv;
    __syncthreads();
    if (tid == 0) cb_s = wsum[0] + wsum[1] + wsum[2] + wsum[3];
    const int lo_s = blockIdx.x * CAP;
    const int hi_s = g_bcur[blockIdx.x];
    for (int j = lo_s + tid; j < hi_s; j += 256)
        atomicAdd(&cnt[staging[j] & BMASK], 1);
    __syncthreads();
    const int colBase = cb_s;
    int v0 = cnt[2 * tid], v1 = cnt[2 * tid + 1];
    int pexcl = block_excl_scan_256(v0 + v1, wsum);
    __syncthreads();
    cnt[2 * tid]     = colBase + pexcl;
    cnt[2 * tid + 1] = colBase + pexcl + v0;
    int node0 = nodeBase + 2 * tid;
    if (node0 < N)     row_ptr[node0]     = colBase + pexcl;
    if (node0 + 1 < N) row_ptr[node0 + 1] = colBase + pexcl + v0;
    __syncthreads();
    for (int j = lo_s + tid; j < hi_s; j += 256) {
        uint32_t rec = staging[j];
        int p = atomicAdd(&cnt[rec & BMASK], 1);
        col_src[p] = (int)(rec >> BSH);
    }
    if (blockIdx.x == 0 && tid == 0) row_ptr[N] = E;
}

// ---------------------------------------------------------------------------
// segment-max over 16-bit sortable code tables (layer 1). 4-deep gather.
// ---------------------------------------------------------------------------
template <int F, int G, int PITCHS>
__global__ __launch_bounds__(256) void agg_max_16(
    const unsigned short* __restrict__ X,
    const int* __restrict__ row_ptr, const int* __restrict__ col_src,
    unsigned short* __restrict__ O, int opitch, int N) {
    static_assert(G == 16 || G == 32, "G must be 16/32");
    constexpr int LOG2G = (G == 16) ? 4 : 5;
    constexpr int EPW = 64 / G;
    const int wave = (blockIdx.x * blockDim.x + threadIdx.x) >> 6;
    const int lane = threadIdx.x & 63;
    if (wave >= N) return;
    const int beg = row_ptr[wave];
    const int end = row_ptr[wave + 1];
    const int l = lane & (G - 1);
    const int grp = lane >> LOG2G;
    const int f0 = l * 8;
    const unsigned short* Xl = X + f0;

    uint32_t t0 = 0, t1 = 0, t2 = 0, t3 = 0;
    auto mrg = [&](uint4 v) {
        t0 = pkmax_u16(t0, v.x); t1 = pkmax_u16(t1, v.y);
        t2 = pkmax_u16(t2, v.z); t3 = pkmax_u16(t3, v.w);
    };
    auto ld = [&](int j) -> uint4 {
        return *(const uint4*)(Xl + (size_t)col_src[j] * PITCHS);
    };

    int j = beg + grp;
    for (; j + 3 * EPW < end; j += 4 * EPW) {      // 4-deep
        uint4 a = ld(j), b = ld(j + EPW), c = ld(j + 2 * EPW), d = ld(j + 3 * EPW);
        mrg(a); mrg(b); mrg(c); mrg(d);
    }
    for (; j + EPW < end; j += 2 * EPW) {
        uint4 a = ld(j), b = ld(j + EPW);
        mrg(a); mrg(b);
    }
    for (; j < end; j += EPW)
        mrg(ld(j));

    #pragma unroll
    for (int off = G; off < 64; off <<= 1) {
        t0 = pkmax_u16(t0, (uint32_t)__shfl_xor((int)t0, off, 64));
        t1 = pkmax_u16(t1, (uint32_t)__shfl_xor((int)t1, off, 64));
        t2 = pkmax_u16(t2, (uint32_t)__shfl_xor((int)t2, off, 64));
        t3 = pkmax_u16(t3, (uint32_t)__shfl_xor((int)t3, off, 64));
    }

    if (grp == 0 && f0 < F) {
        unsigned short* op = O + (size_t)wave * opitch + f0;
        uint4 o = {0u, 0u, 0u, 0u};
        if (beg != end) {
            o.x = dec2(t0); o.y = dec2(t1); o.z = dec2(t2); o.w = dec2(t3);
        }
        *(uint4*)op = o;
    }
}

// ---------------------------------------------------------------------------
// segment-max over the 10-bit packed h1 table (layer 2), perm+pk_max decode.
// 8-deep gather unroll: 16 uint3 gathers in flight per wave.
// ---------------------------------------------------------------------------
__global__ __launch_bounds__(256) void agg_max_10pk(
    const uint32_t* __restrict__ X10,
    const int* __restrict__ row_ptr, const int* __restrict__ col_src,
    unsigned short* __restrict__ O, int opitch, int N) {
    const int wave = (blockIdx.x * blockDim.x + threadIdx.x) >> 6;
    const int lane = threadIdx.x & 63;
    if (wave >= N) return;
    const int beg = row_ptr[wave];
    const int end = row_ptr[wave + 1];
    const int l = lane & 31;
    const int grp = lane >> 5;
    const int f0 = l * 8;
    int db = (5 * l) >> 1;
    if (db > 61) db = 61;                 // pad lanes clamp in-row (discarded)
    const uint32_t qq = (l & 1) ? 0x02020202u : 0u;
    const uint32_t sel02 = 0x03020100u + qq;
    const uint32_t sel13 = 0x04030201u + qq;
    const uint32_t sel57 = 0x05040302u + qq;
    const uint32_t* Xb = X10 + db;

    uint32_t t02 = 0, t13 = 0, t46 = 0, t57 = 0;
    auto mrg = [&](uint32_t A, uint32_t B, uint32_t C) {
        uint32_t u02 = permb(B, A, sel02) & 0x3FF003FFu;   // f0<<0 | f2<<4
        uint32_t u13 = permb(B, A, sel13) & 0xFFC00FFCu;   // f1<<2 | f3<<6
        uint32_t u46 = permb(C, B, sel13) & 0x3FF003FFu;   // f4<<0 | f6<<4
        uint32_t u57 = permb(C, B, sel57) & 0xFFC00FFCu;   // f5<<2 | f7<<6
        t02 = pkmax_u16(t02, u02);
        t13 = pkmax_u16(t13, u13);
        t46 = pkmax_u16(t46, u46);
        t57 = pkmax_u16(t57, u57);
    };
    auto ld = [&](int s) -> uint3 {
        return *(const uint3*)(Xb + ((uint32_t)s << 6));
    };

    int j = beg + grp;
    for (; j + 14 < end; j += 16) {        // 8 gathers in flight per lane
        int s0 = col_src[j],      s1 = col_src[j + 2];
        int s2 = col_src[j + 4],  s3 = col_src[j + 6];
        int s4 = col_src[j + 8],  s5 = col_src[j + 10];
        int s6 = col_src[j + 12], s7 = col_src[j + 14];
        uint3 a = ld(s0), b = ld(s1), c = ld(s2), d = ld(s3);
        uint3 e = ld(s4), f = ld(s5), g = ld(s6), h = ld(s7);
        mrg(a.x, a.y, a.z); mrg(b.x, b.y, b.z);
        mrg(c.x, c.y, c.z); mrg(d.x, d.y, d.z);
        mrg(e.x, e.y, e.z); mrg(f.x, f.y, f.z);
        mrg(g.x, g.y, g.z); mrg(h.x, h.y, h.z);
    }
    for (; j + 6 < end; j += 8) {
        int s0 = col_src[j], s1 = col_src[j + 2];
        int s2 = col_src[j + 4], s3 = col_src[j + 6];
        uint3 a = ld(s0), b = ld(s1), c = ld(s2), d = ld(s3);
        mrg(a.x, a.y, a.z); mrg(b.x, b.y, b.z);
        mrg(c.x, c.y, c.z); mrg(d.x, d.y, d.z);
    }
    for (; j + 2 < end; j += 4) {
        int s0 = col_src[j], s1 = col_src[j + 2];
        uint3 a = ld(s0), b = ld(s1);
        mrg(a.x, a.y, a.z); mrg(b.x, b.y, b.z);
    }
    if (j < end) {
        uint3 a = ld(col_src[j]);
        mrg(a.x, a.y, a.z);
    }

    t02 = pkmax_u16(t02, (uint32_t)__shfl_xor((int)t02, 32, 64));
    t13 = pkmax_u16(t13, (uint32_t)__shfl_xor((int)t13, 32, 64));
    t46 = pkmax_u16(t46, (uint32_t)__shfl_xor((int)t46, 32, 64));
    t57 = pkmax_u16(t57, (uint32_t)__shfl_xor((int)t57, 32, 64));

    if (grp == 0 && f0 < H1D) {
        unsigned short* op = O + (size_t)wave * opitch + f0;
        uint4 o = {0u, 0u, 0u, 0u};
        if (beg != end) {
            unsigned short h[8];
            h[0] = s102b(t02 & 0xFFFFu);
            h[2] = s102b(t02 >> 20);
            h[1] = s102b((t13 & 0xFFFFu) >> 2);
            h[3] = s102b(t13 >> 22);
            h[4] = s102b(t46 & 0xFFFFu);
            h[6] = s102b(t46 >> 20);
            h[5] = s102b((t57 & 0xFFFFu) >> 2);
            h[7] = s102b(t57 >> 22);
            o.x = (uint32_t)h[0] | ((uint32_t)h[1] << 16);
            o.y = (uint32_t)h[2] | ((uint32_t)h[3] << 16);
            o.z = (uint32_t)h[4] | ((uint32_t)h[5] << 16);
            o.w = (uint32_t)h[6] | ((uint32_t)h[7] << 16);
        }
        *(uint4*)op = o;
    }
}

// ---------------------------------------------------------------------------
// MFMA GEMM v6 (unchanged from r5/r8): 64 rows x all M cols per block,
// 8 waves, LDS double-buffer with ONE barrier per K-step.
// ---------------------------------------------------------------------------
template <int NCT, int MODE>
__global__ __launch_bounds__(512) void gemm_mfma_v6(
    const unsigned short* __restrict__ A, int P,
    const unsigned short* __restrict__ Bt,
    const float* __restrict__ bias,
    unsigned short* __restrict__ Cb, int cbPitch, int cbOff,
    uint32_t* __restrict__ X10out,
    unsigned short* __restrict__ Htab,
    int Nrows, int M) {
    constexpr int CHUNK = 2560 + NCT * 640;        // shorts per buffer (As+Bs)
    constexpr int HSZ = (MODE == 1) ? 64 * HP1 : 64 * HP2;
    constexpr int SSZ = (2 * CHUNK > HSZ) ? 2 * CHUNK : HSZ;
    __shared__ short smem[SSZ];
    short* Hs = smem;   // alias; only touched after the final K-loop barrier
    const int tid = threadIdx.x;
    const int wv = tid >> 6;          // 0..7
    const int lane = tid & 63;
    const int q = lane >> 4;
    const int mi = lane & 15;
    const int sp = wv >> 2;           // strip pair: rows [32sp, 32sp+32)
    const int tq = wv & 3;            // tile group: tiles tq+4j
    const int rowBase = blockIdx.x * 64;

    constexpr int TPW = (NCT + 3) / 4;
    f32x4 acc[2][TPW];
    #pragma unroll
    for (int s = 0; s < 2; s++)
        #pragma unroll
        for (int j = 0; j < TPW; j++) acc[s][j] = (f32x4){0.f, 0.f, 0.f, 0.f};

    // staging: slots [0,256) = A (64 rows x 4 segs), [256,..) = B (NCT*64)
    constexpr int ASLOTS = 256;
    constexpr int BSLOTS = NCT * 64;
    constexpr int TSLOTS = ASLOTS + BSLOTS;
    constexpr int SITERS = (TSLOTS + 511) / 512;
    uint4 rS[SITERS];
    auto issue = [&](int kt) {
        #pragma unroll
        for (int i = 0; i < SITERS; i++) {
            int slot = i * 512 + tid;
            rS[i] = (uint4){0u, 0u, 0u, 0u};
            if (slot < ASLOTS) {
                int gr = rowBase + (slot >> 2);
                if (gr < Nrows)
                    rS[i] = *(const uint4*)(A + (size_t)gr * P + kt + (slot & 3) * 8);
            } else if (slot < TSLOTS) {
                int s = slot - ASLOTS, br = s >> 2;
                if (br < M)
                    rS[i] = *(const uint4*)(Bt + (size_t)br * P + kt + (s & 3) * 8);
            }
        }
    };
    auto commit = [&](int buf) {
        short* base = smem + buf * CHUNK;
        #pragma unroll
        for (int i = 0; i < SITERS; i++) {
            int slot = i * 512 + tid;
            if (slot < ASLOTS) {
                *(uint4*)(&base[(slot >> 2) * 40 + (slot & 3) * 8]) = rS[i];
            } else if (slot < TSLOTS) {
                int s = slot - ASLOTS;
                *(uint4*)(&base[2560 + (s >> 2) * 40 + (s & 3) * 8]) = rS[i];
            }
        }
    };

    int cur = 0;
    issue(0); commit(0);
    __syncthreads();
    for (int kt = 0; kt < P; kt += 32) {
        const bool more = (kt + 32) < P;
        if (more) issue(kt + 32);
        const short* As_ = smem + cur * CHUNK;
        const short* Bs_ = As_ + 2560;
        short8 a0 = *(const short8*)(&As_[((2 * sp    ) * 16 + mi) * 40 + q * 8]);
        short8 a1 = *(const short8*)(&As_[((2 * sp + 1) * 16 + mi) * 40 + q * 8]);
        #pragma unroll
        for (int j = 0; j < TPW; j++) {
            int t = tq + 4 * j;               // wave-uniform
            if (t < NCT) {
                short8 b = *(const short8*)(&Bs_[(t * 16 + mi) * 40 + q * 8]);
                acc[0][j] = __builtin_amdgcn_mfma_f32_16x16x32_bf16(a0, b, acc[0][j], 0, 0, 0);
                acc[1][j] = __builtin_amdgcn_mfma_f32_16x16x32_bf16(a1, b, acc[1][j], 0, 0, 0);
            }
        }
        if (more) commit(cur ^ 1);
        __syncthreads();
        cur ^= 1;
    }

    // ---- epilogue: acc -> Hs (LDS transpose; bank-spread pitch) ----
    // D layout: col = lane&15, row = (lane>>4)*4 + reg  [verified m89/m91]
    constexpr int HP = (MODE == 1) ? HP1 : HP2;
    #pragma unroll
    for (int j = 0; j < TPW; j++) {
        int t = tq + 4 * j;
        if (t >= NCT) continue;
        int col = t * 16 + mi;
        if (col >= M) continue;
        float bv = bias[col];
        #pragma unroll
        for (int s = 0; s < 2; s++) {
            int st = 2 * sp + s;
            #pragma unroll
            for (int r = 0; r < 4; r++) {
                int rl = st * 16 + q * 4 + r;
                float v = acc[s][j][r] + bv;
                unsigned short h = f2b(v);
                if constexpr (MODE == 1) Hs[rl * HP + col] = (short)h;
                else                     Hs[rl * HP + col] = (short)enc16(h);
            }
        }
    }
    if constexpr (MODE == 2) {
        // zero Hs pad cols [50,64) -- code 0 is ultra-negative, pk_max-safe
        for (int k = tid; k < 64 * 14; k += 512) {
            int r = k / 14, c = k - r * 14;
            Hs[r * HP2 + H2D + c] = 0;
        }
    }
    __syncthreads();

    if constexpr (MODE == 1) {
        // vectorized Cb write: cols [200,400) from Hs cols [0,200)
        for (int k = tid; k < 64 * 25; k += 512) {
            int r = k / 25, c8 = (k - r * 25) * 8;
            int row = rowBase + r;
            if (row < Nrows) {
                uint2 lo = *(const uint2*)(&Hs[r * HP1 + c8]);
                uint2 hi = *(const uint2*)(&Hs[r * HP1 + c8 + 4]);
                uint4 v = {lo.x, lo.y, hi.x, hi.y};
                *(uint4*)(Cb + (size_t)row * cbPitch + cbOff + c8) = v;
            }
        }
        // zero A2 pad cols [400,416) (vectorized)
        for (int k = tid; k < 64 * 2; k += 512) {
            int r = k >> 1, c = (k & 1) * 8;
            int row = rowBase + r;
            if (row < Nrows)
                *(uint4*)(Cb + (size_t)row * cbPitch + 2 * H1D + c) = (uint4){0u, 0u, 0u, 0u};
        }
        // pack h1 (bf16 in Hs) -> 10-bit sortable table
        for (int k = tid; k < 64 * 13; k += 512) {
            int r = k / 13, g = k - r * 13;
            int row = rowBase + r;
            if (row >= Nrows) continue;
            uint32_t* op = X10out + (size_t)row * X2PD;
            const short* hp = &Hs[r * HP1 + g * 16];
            if (g < 12) {
                uint2 w0 = *(const uint2*)(hp);
                uint2 w1 = *(const uint2*)(hp + 4);
                uint2 w2 = *(const uint2*)(hp + 8);
                uint2 w3 = *(const uint2*)(hp + 12);
                uint32_t t[16];
                t[0]  = b2s10((unsigned short)(w0.x)); t[1]  = b2s10((unsigned short)(w0.x >> 16));
                t[2]  = b2s10((unsigned short)(w0.y)); t[3]  = b2s10((unsigned short)(w0.y >> 16));
                t[4]  = b2s10((unsigned short)(w1.x)); t[5]  = b2s10((unsigned short)(w1.x >> 16));
                t[6]  = b2s10((unsigned short)(w1.y)); t[7]  = b2s10((unsigned short)(w1.y >> 16));
                t[8]  = b2s10((unsigned short)(w2.x)); t[9]  = b2s10((unsigned short)(w2.x >> 16));
                t[10] = b2s10((unsigned short)(w2.y)); t[11] = b2s10((unsigned short)(w2.y >> 16));
                t[12] = b2s10((unsigned short)(w3.x)); t[13] = b2s10((unsigned short)(w3.x >> 16));
                t[14] = b2s10((unsigned short)(w3.y)); t[15] = b2s10((unsigned short)(w3.y >> 16));
                uint32_t d[5];
                pack10x16(t, d);
                #pragma unroll
                for (int i = 0; i < 5; i++) op[g * 5 + i] = d[i];
            } else {
                uint2 w0 = *(const uint2*)(hp);
                uint2 w1 = *(const uint2*)(hp + 4);
                uint32_t t[8];
                t[0] = b2s10((unsigned short)(w0.x)); t[1] = b2s10((unsigned short)(w0.x >> 16));
                t[2] = b2s10((unsigned short)(w0.y)); t[3] = b2s10((unsigned short)(w0.y >> 16));
                t[4] = b2s10((unsigned short)(w1.x)); t[5] = b2s10((unsigned short)(w1.x >> 16));
                t[6] = b2s10((unsigned short)(w1.y)); t[7] = b2s10((unsigned short)(w1.y >> 16));
                uint32_t d0 = t[0] | (t[1] << 10) | (t[2] << 20) | (t[3] << 30);
                uint32_t d1 = (t[3] >> 2) | (t[4] << 8) | (t[5] << 18) | (t[6] << 28);
                uint32_t d2 = (t[6] >> 4) | (t[7] << 6);
                op[60] = d0; op[61] = d1; op[62] = d2;
            }
        }
    }
    if constexpr (MODE == 2) {
        // vectorized Htab write (cols 0..63 incl. zeroed pads)
        for (int k = tid; k < 64 * 8; k += 512) {
            int r = k >> 3, c8 = (k & 7) * 8;
            int row = rowBase + r;
            if (row < Nrows) {
                uint2 lo = *(const uint2*)(&Hs[r * HP2 + c8]);
                uint2 hi = *(const uint2*)(&Hs[r * HP2 + c8 + 4]);
                uint4 v = {lo.x, lo.y, hi.x, hi.y};
                *(uint4*)(Htab + (size_t)row * 64 + c8) = v;
            }
        }
    }
}

// ---------------------------------------------------------------------------
// Layer 3 fully fused (unchanged from r8, 4-deep gather)
// ---------------------------------------------------------------------------
__global__ __launch_bounds__(256) void layer3_fused(
    const unsigned short* __restrict__ Htab,
    const int* __restrict__ row_ptr, const int* __restrict__ col_src,
    const unsigned short* __restrict__ Bt,
    const float* __restrict__ bias,
    float* __restrict__ out, int N) {
    __shared__ short As[64 * 136];
    __shared__ short Bs[640];
    const int tid = threadIdx.x;
    const int wv = tid >> 6;
    const int lane = tid & 63;
    const int rowBase = blockIdx.x * 64;

    {
        const int l = lane & 7;
        const int grp = lane >> 3;
        const int f0 = l * 8;
        const unsigned short* Hl = Htab + f0;
        for (int n = 0; n < 16; n++) {
            int node = rowBase + wv * 16 + n;
            int beg = 0, end = 0;
            if (node < N) { beg = row_ptr[node]; end = row_ptr[node + 1]; }
            uint32_t t0 = 0, t1 = 0, t2 = 0, t3 = 0;
            auto mrg = [&](uint4 v) {
                t0 = pkmax_u16(t0, v.x); t1 = pkmax_u16(t1, v.y);
                t2 = pkmax_u16(t2, v.z); t3 = pkmax_u16(t3, v.w);
            };
            auto ld = [&](int j) -> uint4 {
                return *(const uint4*)(Hl + (size_t)col_src[j] * 64);
            };
            int j = beg + grp;
            for (; j + 24 < end; j += 32) {            // 4-deep
                uint4 v0 = ld(j), v1 = ld(j + 8), v2 = ld(j + 16), v3 = ld(j + 24);
                mrg(v0); mrg(v1); mrg(v2); mrg(v3);
            }
            for (; j + 8 < end; j += 16) {
                uint4 v0 = ld(j), v1 = ld(j + 8);
                mrg(v0); mrg(v1);
            }
            if (j < end) mrg(ld(j));
            #pragma unroll
            for (int off = 8; off < 64; off <<= 1) {
                t0 = pkmax_u16(t0, (uint32_t)__shfl_xor((int)t0, off, 64));
                t1 = pkmax_u16(t1, (uint32_t)__shfl_xor((int)t1, off, 64));
                t2 = pkmax_u16(t2, (uint32_t)__shfl_xor((int)t2, off, 64));
                t3 = pkmax_u16(t3, (uint32_t)__shfl_xor((int)t3, off, 64));
            }
            if (grp == 0 && f0 < H2D) {
                short* op = &As[(wv * 16 + n) * 136];
                const bool empty = (beg == end);
                if (f0 + 8 <= H2D) {
                    uint4 o = {0u, 0u, 0u, 0u};
                    if (!empty) {
                        o.x = dec2(t0); o.y = dec2(t1);
                        o.z = dec2(t2); o.w = dec2(t3);
                    }
                    *(uint4*)(op + f0) = o;
                } else {  // l==6: cols 48,49 only
                    uint32_t o2 = empty ? 0u : dec2(t0);
                    *(uint32_t*)(op + f0) = o2;
                }
            }
        }
    }
    for (int k = tid; k < 64 * 25; k += 256) {
        int r = k / 25, c = (k - r * 25) * 2;
        int node = rowBase + r;
        uint32_t v = 0;
        if (node < N) v = dec2(*(const uint32_t*)(Htab + (size_t)node * 64 + c));
        *(uint32_t*)(&As[r * 136 + H2OFF + c]) = v;
    }
    for (int k = tid; k < 64 * 28; k += 256) {
        int r = k / 28, c = k - r * 28;
        int col = (c < 6) ? (50 + c) : (100 + c);
        As[r * 136 + col] = 0;
    }
    __syncthreads();

    const int q = lane >> 4;
    const int mi = lane & 15;
    f32x4 acc = (f32x4){0.f, 0.f, 0.f, 0.f};
    for (int kt = 0; kt < P3; kt += 32) {
        if (tid < 64) {
            int br = tid >> 2;
            int bs = tid & 3;
            uint4 vb = {0u, 0u, 0u, 0u};
            if (br < NCLS) vb = *(const uint4*)(Bt + (size_t)br * P3 + kt + bs * 8);
            *(uint4*)(&Bs[br * 40 + bs * 8]) = vb;
        }
        __syncthreads();
        short8 a = *(const short8*)(&As[(wv * 16 + mi) * 136 + kt + q * 8]);
        short8 b = *(const short8*)(&Bs[mi * 40 + q * 8]);
        acc = __builtin_amdgcn_mfma_f32_16x16x32_bf16(a, b, acc, 0, 0, 0);
        __syncthreads();
    }

    float bv = (mi < NCLS) ? bias[mi] : 0.0f;
    #pragma unroll
    for (int r = 0; r < 4; r++) {
        float v = acc[r] + bv;
        float mx = (mi < NCLS) ? v : -INFINITY;
        #pragma unroll
        for (int off = 1; off < 16; off <<= 1)
            mx = fmaxf(mx, __shfl_xor(mx, off, 64));
        float ex = (mi < NCLS) ? expf(v - mx) : 0.0f;
        float sm = ex;
        #pragma unroll
        for (int off = 1; off < 16; off <<= 1)
            sm += __shfl_xor(sm, off, 64);
        int row = rowBase + wv * 16 + q * 4 + r;
        if (mi < NCLS && row < N)
            out[(size_t)row * NCLS + mi] = v - mx - logf(sm);
    }
}

// ---------------------------------------------------------------------------
extern "C" void kernel_launch(void* const* d_in, const int* in_sizes, int n_in,
                              void* d_out, int out_size, void* d_ws, size_t ws_size,
                              hipStream_t stream) {
    const float* x    = (const float*)d_in[0];
    const int*   eidx = (const int*)d_in[1];
    const float* Wl1  = (const float*)d_in[2];
    const float* b1   = (const float*)d_in[3];
    const float* Wr1  = (const float*)d_in[4];
    const float* Wl2  = (const float*)d_in[5];
    const float* b2   = (const float*)d_in[6];
    const float* Wr2  = (const float*)d_in[7];
    const float* Wl3  = (const float*)d_in[8];
    const float* b3   = (const float*)d_in[9];
    const float* Wr3  = (const float*)d_in[10];
    const int* srcp = eidx;
    const int* dstp = eidx + N_EDGES;
    float* out = (float*)d_out;
    (void)ws_size; (void)in_sizes; (void)n_in; (void)out_size;

    char* w = (char*)d_ws;
    size_t off = 0;
    auto alloc = [&](size_t bytes) -> char* {
        char* p = w + off;
        off += (bytes + 255) & ~(size_t)255;
        return p;
    };
    int* g_bcur   = (int*)alloc(sizeof(int) * 256);
    int* row_ptr  = (int*)alloc(sizeof(int) * (N_NODES + 1));
    int* col_src  = (int*)alloc(sizeof(int) * N_EDGES);
    // staging now has its OWN buffer (7.3 MB) so prep_all (which writes
    // X16_1 into Z) can run BEFORE the CSR chain.
    uint32_t* staging = (uint32_t*)alloc(sizeof(uint32_t) * (size_t)NB * CAP);
    // Union region Z (32 MB), sequential lifetimes on the serial stream:
    //   X16_1 (25.6 MB, written by prep_all, dead after agg1)
    //   -> X10_2 (25.6 MB, written by gemm1, dead after agg2)
    char* Z = alloc(32u * 1024 * 1024);
    unsigned short* X16_1  = (unsigned short*)Z;
    uint32_t* X10_2        = (uint32_t*)Z;
    unsigned short* A1  = (unsigned short*)alloc(sizeof(short) * (size_t)N_NODES * P1);
    unsigned short* A2  = (unsigned short*)alloc(sizeof(short) * (size_t)N_NODES * P2);
    unsigned short* Bt1 = (unsigned short*)alloc(sizeof(short) * H1D * P1);
    unsigned short* Bt2 = (unsigned short*)alloc(sizeof(short) * H2D * P2);
    unsigned short* Bt3 = (unsigned short*)alloc(sizeof(short) * NCLS * P3);
    // h2 code gather table (12.8 MB) overlays A1 (dead after gemm1).
    unsigned short* X16_3 = A1;

    // ---- launch 1: fused prep (csr_init + weight tables + x conversion) ----
    constexpr int S1 = H1D * P1, S2 = H2D * P2, S3 = NCLS * P3;
    constexpr int BT_BLOCKS = (S1 + S2 + S3 + 255) / 256;
    const int CONV_BLOCKS = (N_NODES * 16 + 255) / 256;
    prep_all<<<BT_BLOCKS + CONV_BLOCKS, 256, 0, stream>>>(
        Wl1, Wr1, Wl2, Wr2, Wl3, Wr3, Bt1, Bt2, Bt3, x, A1, X16_1, g_bcur, N_NODES);

    // ---- launches 2-3: CSR build (bscan folded into csr_p2) ----
    const int EDGE_BLKS = (N_EDGES + EPB - 1) / EPB;
    csr_p1<<<EDGE_BLKS, 256, 0, stream>>>(srcp, dstp, g_bcur, staging, N_EDGES);
    csr_p2<<<NB, 256, 0, stream>>>(staging, g_bcur, row_ptr, col_src, N_NODES, N_EDGES);

    const int aggBlocks = (N_NODES + 3) / 4;
    const int rowTiles64 = (N_NODES + 63) / 64;

    // ---- layer 1: u16-code agg(x) -> gemm1 (h1 -> A2 + fused 10-bit pack) --
    agg_max_16<F_IN, 16, 128><<<aggBlocks, 256, 0, stream>>>(X16_1, row_ptr, col_src, A1, P1, N_NODES);
    gemm_mfma_v6<13, 1><<<rowTiles64, 512, 0, stream>>>(A1, P1, Bt1, b1, A2, P2, H1D, X10_2, nullptr, N_NODES, H1D);

    // ---- layer 2: 10-bit perm/pk agg(h1) -> gemm2 (h2 -> u16 code table) ----
    agg_max_10pk<<<aggBlocks, 256, 0, stream>>>(X10_2, row_ptr, col_src, A2, P2, N_NODES);
    gemm_mfma_v6<4, 2><<<rowTiles64, 512, 0, stream>>>(A2, P2, Bt2, b2, nullptr, 0, 0, nullptr, X16_3, N_NODES, H2D);

    // ---- layer 3: fully fused gather + GEMM + log_softmax -> out ----
    layer3_fused<<<rowTiles64, 256, 0, stream>>>(X16_3, row_ptr, col_src, Bt3, b3, out, N_NODES);
}